// Round 16
// baseline (4936.011 us; speedup 1.0000x reference)
//
#include <hip/hip_runtime.h>
#include <hip/hip_bf16.h>
#include <math.h>

#define SEQ 1024
#define DIM 4096
#define NH 32
#define HD 128
#define NKVH 8
#define FF 14336
#define LR 16

typedef __attribute__((ext_vector_type(8))) short bf16x8;
typedef __attribute__((ext_vector_type(4))) float f32x4;
typedef __attribute__((ext_vector_type(4))) ushort ushort4v;
typedef __attribute__((ext_vector_type(4))) unsigned int u32x4;

__device__ __forceinline__ ushort f2bf(float f) {
  union { float f; unsigned u; } v; v.f = f;
  unsigned r = (v.u + 0x7FFFu + ((v.u >> 16) & 1u)) >> 16;
  return (ushort)r;
}
__device__ __forceinline__ float bf2f(ushort h) {
  union { unsigned u; float f; } v; v.u = ((unsigned)h) << 16;
  return v.f;
}
__device__ __forceinline__ unsigned cvtpk(float a, float b) {
  unsigned r;
  asm("v_cvt_pk_bf16_f32 %0, %1, %2" : "=v"(r) : "v"(a), "v"(b));
  return r;
}

__device__ __forceinline__ void gload_lds16(const void* g, void* l) {
  __builtin_amdgcn_global_load_lds(
      (const __attribute__((address_space(1))) void*)g,
      (__attribute__((address_space(3))) void*)l, 16, 0, 0);
}

// ---------------- RMSNorm: f32 in -> bf16 out ----------------
__global__ __launch_bounds__(256) void rmsnorm_kernel(const float* __restrict__ x,
                                                      const float* __restrict__ w,
                                                      ushort* __restrict__ out) {
  int row = blockIdx.x;
  int tid = threadIdx.x;
  const float* xr = x + (size_t)row * DIM;
  float vals[16];
  float s = 0.f;
#pragma unroll
  for (int c = 0; c < 4; c++) {
    float4 v = *(const float4*)&xr[(tid + c * 256) * 4];
    vals[c * 4 + 0] = v.x; vals[c * 4 + 1] = v.y;
    vals[c * 4 + 2] = v.z; vals[c * 4 + 3] = v.w;
    s += v.x * v.x + v.y * v.y + v.z * v.z + v.w * v.w;
  }
#pragma unroll
  for (int off = 32; off >= 1; off >>= 1) s += __shfl_down(s, off);
  __shared__ float wsum[4];
  __shared__ float scale_s;
  int lane = tid & 63, wv = tid >> 6;
  if (lane == 0) wsum[wv] = s;
  __syncthreads();
  if (tid == 0) {
    float t = wsum[0] + wsum[1] + wsum[2] + wsum[3];
    scale_s = rsqrtf(t / (float)DIM + 1e-5f);
  }
  __syncthreads();
  float scale = scale_s;
  ushort* orow = out + (size_t)row * DIM;
#pragma unroll
  for (int c = 0; c < 4; c++) {
    int base = (tid + c * 256) * 4;
    float4 wv4 = *(const float4*)&w[base];
    ushort4v ov;
    ov.x = f2bf(vals[c * 4 + 0] * scale * wv4.x);
    ov.y = f2bf(vals[c * 4 + 1] * scale * wv4.y);
    ov.z = f2bf(vals[c * 4 + 2] * scale * wv4.z);
    ov.w = f2bf(vals[c * 4 + 3] * scale * wv4.w);
    *(ushort4v*)&orow[base] = ov;
  }
}

// ---------------- LoRA A: t_l[m][16] = A[m] @ la_l, one row per block ----------------
template <int NL>
__global__ __launch_bounds__(256) void lora_a_kernel(
    const ushort* __restrict__ A,
    const float* __restrict__ la0, const float* __restrict__ la1,
    const float* __restrict__ la2,
    ushort* __restrict__ t0, ushort* __restrict__ t1, ushort* __restrict__ t2,
    int K) {
  int m = blockIdx.x, i = threadIdx.x;
  float acc[NL][16];
#pragma unroll
  for (int l = 0; l < NL; l++)
#pragma unroll
    for (int n = 0; n < 16; n++) acc[l][n] = 0.f;

  const ushort* Arow = A + (size_t)m * K;
  int nc = K >> 8;
  for (int c = 0; c < nc; c++) {
    int k = c * 256 + i;
    float a = bf2f(Arow[k]);
#pragma unroll
    for (int l = 0; l < NL; l++) {
      const float* lap = (l == 0 ? la0 : (l == 1 ? la1 : la2)) + (size_t)k * 16;
#pragma unroll
      for (int q = 0; q < 4; q++) {
        float4 lv = *(const float4*)&lap[q * 4];
        acc[l][q * 4 + 0] += a * lv.x;
        acc[l][q * 4 + 1] += a * lv.y;
        acc[l][q * 4 + 2] += a * lv.z;
        acc[l][q * 4 + 3] += a * lv.w;
      }
    }
  }

  __shared__ float red[256][17];
  __shared__ float red2[16][17];
#pragma unroll
  for (int l = 0; l < NL; l++) {
    __syncthreads();
#pragma unroll
    for (int n = 0; n < 16; n++) red[i][n] = acc[l][n];
    __syncthreads();
    {
      int g = i >> 4, n = i & 15;
      float s = 0.f;
#pragma unroll
      for (int j = 0; j < 16; j++) s += red[g * 16 + j][n];
      red2[g][n] = s;
    }
    __syncthreads();
    if (i < 16) {
      float s2 = 0.f;
#pragma unroll
      for (int g2 = 0; g2 < 16; g2++) s2 += red2[g2][i];
      ushort* tp = (l == 0 ? t0 : (l == 1 ? t1 : t2));
      tp[(size_t)m * LR + i] = f2bf(s2);
    }
  }
}

// ================= 256x256 GEMM, 8 waves, SINGLE-BUFFER LDS (64KB -> 2 blocks/CU) =================
// m97/m114 mechanism: intra-block stall at tile boundary is covered by the co-resident
// block's waves. B f32 loads issued mid-compute (regs); A gload_lds at tile boundary.
// cvt_pk dequant; panel-sharer co-location; XOR swizzle both sides.
// WM 0: bf16 [M][N]; WM 3: f32 partial [z][M][N]; WM 4: bf16 silu(gate)*v
template <int WM>
__global__ __launch_bounds__(512, 4) void gemm256_kernel(
    const ushort* __restrict__ A,
    const float* __restrict__ W0, const float* __restrict__ W1, const float* __restrict__ W2,
    const float* __restrict__ lb0, const float* __restrict__ lb1, const float* __restrict__ lb2,
    const ushort* __restrict__ t0, const ushort* __restrict__ t1, const ushort* __restrict__ t2,
    const ushort* __restrict__ gatep,
    int c1, int c2, void* __restrict__ outp, int M, int N, int K, int nkp) {
  __shared__ __align__(16) ushort As[256 * 64];
  __shared__ __align__(16) ushort Bs[256 * 64];
  int tid = threadIdx.x;
  int lane = tid & 63, wave = tid >> 6;
  int wm = wave >> 2, wn = wave & 3;

  // ---- T1 XCD swizzle + panel-sharer-adjacent decode ----
  int gx = gridDim.x, gy = gridDim.y, gz = gridDim.z;
  int flat = blockIdx.x + gx * (blockIdx.y + gy * blockIdx.z);
  int nwg = gx * gy * gz;
  int q = nwg >> 3, r = nwg & 7;
  int xcd = flat & 7;
  int wgid = (xcd < r ? xcd * (q + 1) : r * (q + 1) + (xcd - r) * q) + (flat >> 3);
  int sh = gy * gz;
  int bx = wgid / sh;
  int rem = wgid - bx * sh;
  int z = rem / gy;
  int by = rem - z * gy;

  int n0 = bx * 256, m0 = by * 256;
  int k0 = z * nkp;

  // segment select (weight + lora)
  const float* Wp; const float* lbp; const ushort* tp; int nseg, wseg;
  if (n0 < c1)      { Wp = W0; lbp = lb0; tp = t0; nseg = n0;      wseg = c1; }
  else if (n0 < c2) { Wp = W1; lbp = lb1; tp = t1; nseg = n0 - c1; wseg = c2 - c1; }
  else              { Wp = W2; lbp = lb2; tp = t2; nseg = n0 - c2; wseg = N - c2; }

  // A staging
  int srow = tid >> 3;
  int sswz = ((tid & 7) ^ (srow & 7)) * 8;
  const ushort* Ab = A + (size_t)(m0 + srow) * K + sswz;
  // B reg-staging source (linear; swizzle at ds_write)
  const float* Wbase = Wp + (size_t)(nseg + srow) * K + (tid & 7) * 8;

  f32x4 acc[8][4] = {};
  float4 breg[8];

#define SHALF_A(kt, h)                                                        \
  _Pragma("unroll") for (int i = 2 * (h); i < 2 * (h) + 2; i++) {             \
    gload_lds16(Ab + (size_t)(i * 64) * K + (size_t)(kt) * 64,                \
                &As[wave * 512 + i * 4096]);                                  \
  }
#define BLOAD(kt, h)                                                          \
  {                                                                           \
    const float* gp = Wbase + (size_t)((h) * 128) * K + (size_t)(kt) * 64;    \
    breg[(h) * 4 + 0] = *(const float4*)gp;                                   \
    breg[(h) * 4 + 1] = *(const float4*)(gp + 4);                             \
    breg[(h) * 4 + 2] = *(const float4*)(gp + (size_t)64 * K);                \
    breg[(h) * 4 + 3] = *(const float4*)(gp + (size_t)64 * K + 4);            \
  }
#define WRITE_B()                                                             \
  _Pragma("unroll") for (int h = 0; h < 2; h++)                               \
  _Pragma("unroll") for (int j = 0; j < 2; j++) {                             \
    int rr = h * 128 + j * 64 + srow;                                         \
    float4 lo = breg[h * 4 + j * 2 + 0];                                      \
    float4 hi = breg[h * 4 + j * 2 + 1];                                      \
    u32x4 v;                                                                  \
    v.x = cvtpk(lo.x, lo.y); v.y = cvtpk(lo.z, lo.w);                         \
    v.z = cvtpk(hi.x, hi.y); v.w = cvtpk(hi.z, hi.w);                         \
    *(u32x4*)&Bs[rr * 64 + (((tid & 7) ^ (rr & 7))) * 8] = v;                 \
  }
#define LDFRAG(buf, rr, ks) \
  (*(const bf16x8*)&(buf)[(rr) * 64 + (((ks) * 4 + (lane >> 4)) ^ ((rr) & 7)) * 8])

  // ---- prologue: stage tile 0 ----
  BLOAD(k0, 0); BLOAD(k0, 1);
  SHALF_A(k0, 0); SHALF_A(k0, 1);
  asm volatile("s_waitcnt vmcnt(4)" ::: "memory");  // B(0) landed; A(0) in flight
  WRITE_B();
  asm volatile("s_waitcnt vmcnt(0) lgkmcnt(0)" ::: "memory");
  __builtin_amdgcn_s_barrier();
  __builtin_amdgcn_sched_barrier(0);

  for (int tau = 0; tau < nkp; tau++) {
    bool s1 = (tau + 1 < nkp);
    // ---- compute: 4 quadrant phases, no barriers (LDS stable); B(tau+1) issued mid-way ----
    bf16x8 bfr[4][2];
#pragma unroll
    for (int p = 0; p < 4; p++) {
      bf16x8 af[2][2];
#pragma unroll
      for (int qq = 0; qq < 2; qq++) {
        int ra = wm * 128 + (p * 2 + qq) * 16 + (lane & 15);
#pragma unroll
        for (int ks = 0; ks < 2; ks++) af[qq][ks] = LDFRAG(As, ra, ks);
      }
      if (p == 0) {
#pragma unroll
        for (int f = 0; f < 4; f++) {
          int rb = wn * 64 + f * 16 + (lane & 15);
#pragma unroll
          for (int ks = 0; ks < 2; ks++) bfr[f][ks] = LDFRAG(Bs, rb, ks);
        }
      }
      if (p == 2 && s1) { BLOAD(k0 + tau + 1, 0); }
      if (p == 3 && s1) { BLOAD(k0 + tau + 1, 1); }
      __builtin_amdgcn_s_setprio(1);
#pragma unroll
      for (int qq = 0; qq < 2; qq++)
#pragma unroll
        for (int fn = 0; fn < 4; fn++)
#pragma unroll
          for (int ks = 0; ks < 2; ks++)
            acc[p * 2 + qq][fn] = __builtin_amdgcn_mfma_f32_16x16x32_bf16(
                af[qq][ks], bfr[fn][ks], acc[p * 2 + qq][fn], 0, 0, 0);
      __builtin_amdgcn_s_setprio(0);
    }
    // ---- tile boundary: all waves done reading; restage ----
    __builtin_amdgcn_sched_barrier(0);
    __builtin_amdgcn_s_barrier();
    if (s1) {
      SHALF_A(k0 + tau + 1, 0); SHALF_A(k0 + tau + 1, 1);
      asm volatile("s_waitcnt vmcnt(4)" ::: "memory");  // B(tau+1) regs landed; A in flight
      WRITE_B();
      asm volatile("s_waitcnt vmcnt(0) lgkmcnt(0)" ::: "memory");
    }
    __builtin_amdgcn_s_barrier();
    __builtin_amdgcn_sched_barrier(0);
  }
#undef SHALF_A
#undef BLOAD
#undef WRITE_B

  // ---- LoRA K-extension (split 0 only) ----
  if (z == 0) {
#pragma unroll
    for (int it = 0; it < 2; it++) {
      int task = tid + it * 512;
      int rr = task >> 2, ls = task & 3;
      int ph = ls ^ (rr & 7);
      bf16x8 avv = {};
      bf16x8 bvv = {};
      if (ls < 2) {
        avv = *(const bf16x8*)&tp[(size_t)(m0 + rr) * LR + ls * 8];
#pragma unroll
        for (int j = 0; j < 8; j++)
          bvv[j] = (short)f2bf(lbp[(size_t)(ls * 8 + j) * wseg + nseg + rr]);
      }
      *(bf16x8*)&As[rr * 64 + ph * 8] = avv;
      *(bf16x8*)&Bs[rr * 64 + ph * 8] = bvv;
    }
    __syncthreads();
    bf16x8 af[8], bfr[4];
#pragma unroll
    for (int f = 0; f < 8; f++) {
      int ra = wm * 128 + f * 16 + (lane & 15);
      af[f] = LDFRAG(As, ra, 0);
    }
#pragma unroll
    for (int f = 0; f < 4; f++) {
      int rb = wn * 64 + f * 16 + (lane & 15);
      bfr[f] = LDFRAG(Bs, rb, 0);
    }
#pragma unroll
    for (int fm = 0; fm < 8; fm++)
#pragma unroll
      for (int fn = 0; fn < 4; fn++)
        acc[fm][fn] = __builtin_amdgcn_mfma_f32_16x16x32_bf16(af[fm], bfr[fn], acc[fm][fn], 0, 0, 0);
  }
#undef LDFRAG

  // ---- write ----
#pragma unroll
  for (int fm = 0; fm < 8; fm++) {
#pragma unroll
    for (int j = 0; j < 4; j++) {
      int mg = m0 + wm * 128 + fm * 16 + (lane >> 4) * 4 + j;
#pragma unroll
      for (int fn = 0; fn < 4; fn++) {
        int ng = n0 + wn * 64 + fn * 16 + (lane & 15);
        float v = acc[fm][fn][j];
        if (WM == 0) {
          ((ushort*)outp)[(size_t)mg * N + ng] = f2bf(v);
        } else if (WM == 4) {
          float g = bf2f(gatep[(size_t)mg * N + ng]);
          float sv = g / (1.f + __expf(-g));
          ((ushort*)outp)[(size_t)mg * N + ng] = f2bf(sv * v);
        } else {
          ((float*)outp)[((size_t)z * M + mg) * (size_t)N + ng] = v;
        }
      }
    }
  }
}

// ---------------- QKV reduce + fused RoPE (q scaled) + V transpose ----------------
__global__ __launch_bounds__(256) void reduce2_qkv_rope(const float* __restrict__ p,
                                                        const float* __restrict__ ct,
                                                        const float* __restrict__ st,
                                                        ushort* __restrict__ qb,
                                                        ushort* __restrict__ kb,
                                                        ushort* __restrict__ vtb) {
  int gidx = blockIdx.x * 256 + threadIdx.x;
  int r = gidx / 896, j = gidx - r * 896;
  size_t row = (size_t)r * 6144;
  size_t sstride = (size_t)SEQ * 6144;
  if (j < 640) {
    bool isq = j < 512;
    int jj = isq ? j : j - 512;
    int h = jj >> 4, d0 = (jj & 15) * 4;
    size_t base = row + (isq ? 0 : DIM) + h * 128 + d0;
    float4 a1 = *(const float4*)&p[base];
    float4 b1 = *(const float4*)&p[base + sstride];
    float4 a2 = *(const float4*)&p[base + 64];
    float4 b2 = *(const float4*)&p[base + 64 + sstride];
    float4 x1, x2;
    x1.x = a1.x + b1.x; x1.y = a1.y + b1.y; x1.z = a1.z + b1.z; x1.w = a1.w + b1.w;
    x2.x = a2.x + b2.x; x2.y = a2.y + b2.y; x2.z = a2.z + b2.z; x2.w = a2.w + b2.w;
    float4 c = *(const float4*)&ct[r * HD + d0];
    float4 s = *(const float4*)&st[r * HD + d0];
    float sc = isq ? 0.08838834764831845f : 1.0f;
    ushort4v o1, o2;
    o1.x = f2bf((x1.x * c.x - x2.x * s.x) * sc);
    o1.y = f2bf((x1.y * c.y - x2.y * s.y) * sc);
    o1.z = f2bf((x1.z * c.z - x2.z * s.z) * sc);
    o1.w = f2bf((x1.w * c.w - x2.w * s.w) * sc);
    o2.x = f2bf((x2.x * c.x + x1.x * s.x) * sc);
    o2.y = f2bf((x2.y * c.y + x1.y * s.y) * sc);
    o2.z = f2bf((x2.z * c.z + x1.z * s.z) * sc);
    o2.w = f2bf((x2.w * c.w + x1.w * s.w) * sc);
    if (isq) {
      *(ushort4v*)&qb[(size_t)r * DIM + h * 128 + d0] = o1;
      *(ushort4v*)&qb[(size_t)r * DIM + h * 128 + d0 + 64] = o2;
    } else {
      *(ushort4v*)&kb[(size_t)r * 1024 + h * 128 + d0] = o1;
      *(ushort4v*)&kb[(size_t)r * 1024 + h * 128 + d0 + 64] = o2;
    }
  } else {
    int jj = j - 640;
    int c0 = jj * 4;
    size_t base = row + DIM + 1024 + c0;
    float4 a = *(const float4*)&p[base];
    float4 b = *(const float4*)&p[base + sstride];
    vtb[(size_t)(c0 + 0) * SEQ + r] = f2bf(a.x + b.x);
    vtb[(size_t)(c0 + 1) * SEQ + r] = f2bf(a.y + b.y);
    vtb[(size_t)(c0 + 2) * SEQ + r] = f2bf(a.z + b.z);
    vtb[(size_t)(c0 + 3) * SEQ + r] = f2bf(a.w + b.w);
  }
}

// ---------------- split-K reduce + residual -> f32 out ----------------
__global__ __launch_bounds__(256) void reduce4_res_kernel(const float* __restrict__ p,
                                                          const float* __restrict__ res,
                                                          float* __restrict__ out,
                                                          size_t sstride) {
  size_t i = ((size_t)blockIdx.x * 256 + threadIdx.x) * 4;
  float4 a = *(const float4*)&p[i];
  float4 b = *(const float4*)&p[i + sstride];
  float4 c = *(const float4*)&p[i + 2 * sstride];
  float4 d = *(const float4*)&p[i + 3 * sstride];
  float4 r = *(const float4*)&res[i];
  float4 o;
  o.x = a.x + b.x + c.x + d.x + r.x;
  o.y = a.y + b.y + c.y + d.y + r.y;
  o.z = a.z + b.z + c.z + d.z + r.z;
  o.w = a.w + b.w + c.w + d.w + r.w;
  *(float4*)&out[i] = o;
}

// ---------------- split-K reduce + residual + fused RMSNorm (one row/block) ----------------
__global__ __launch_bounds__(256) void reduce4_res_rms(const float* __restrict__ p,
                                                       const float* __restrict__ res,
                                                       const float* __restrict__ w,
                                                       float* __restrict__ xmed,
                                                       ushort* __restrict__ xn2,
                                                       size_t sstride) {
  int row = blockIdx.x, tid = threadIdx.x;
  size_t base = (size_t)row * DIM;
  float vals[16];
  float sq = 0.f;
#pragma unroll
  for (int c = 0; c < 4; c++) {
    size_t i = base + (tid + c * 256) * 4;
    float4 a = *(const float4*)&p[i];
    float4 b = *(const float4*)&p[i + sstride];
    float4 cc = *(const float4*)&p[i + 2 * sstride];
    float4 d = *(const float4*)&p[i + 3 * sstride];
    float4 r = *(const float4*)&res[i];
    float4 v;
    v.x = a.x + b.x + cc.x + d.x + r.x;
    v.y = a.y + b.y + cc.y + d.y + r.y;
    v.z = a.z + b.z + cc.z + d.z + r.z;
    v.w = a.w + b.w + cc.w + d.w + r.w;
    *(float4*)&xmed[i] = v;
    vals[c * 4 + 0] = v.x; vals[c * 4 + 1] = v.y;
    vals[c * 4 + 2] = v.z; vals[c * 4 + 3] = v.w;
    sq += v.x * v.x + v.y * v.y + v.z * v.z + v.w * v.w;
  }
#pragma unroll
  for (int off = 32; off >= 1; off >>= 1) sq += __shfl_down(sq, off);
  __shared__ float wsum[4];
  __shared__ float scale_s;
  int lane = tid & 63, wv = tid >> 6;
  if (lane == 0) wsum[wv] = sq;
  __syncthreads();
  if (tid == 0) {
    float t = wsum[0] + wsum[1] + wsum[2] + wsum[3];
    scale_s = rsqrtf(t / (float)DIM + 1e-5f);
  }
  __syncthreads();
  float scale = scale_s;
#pragma unroll
  for (int c = 0; c < 4; c++) {
    int off = (tid + c * 256) * 4;
    float4 wv4 = *(const float4*)&w[off];
    ushort4v ov;
    ov.x = f2bf(vals[c * 4 + 0] * scale * wv4.x);
    ov.y = f2bf(vals[c * 4 + 1] * scale * wv4.y);
    ov.z = f2bf(vals[c * 4 + 2] * scale * wv4.z);
    ov.w = f2bf(vals[c * 4 + 3] * scale * wv4.w);
    *(ushort4v*)&xn2[base + off] = ov;
  }
}

// ---------------- Flash attention (causal, GQA 4:1), kvh-XCD co-located, LPT order ----------------
__global__ __launch_bounds__(256) void attn_kernel(const ushort* __restrict__ q,
                                                   const ushort* __restrict__ k,
                                                   const ushort* __restrict__ vt,
                                                   ushort* __restrict__ o) {
  int flat = blockIdx.x + 16 * blockIdx.y;  // 0..511
  int kvh = flat & 7;
  int idx = flat >> 3;
  int h = kvh * 4 + (idx & 3);
  int qb = 15 - (idx >> 2);                 // descending work order
  int tid = threadIdx.x, lane = tid & 63, wave = tid >> 6;
  __shared__ ushort Ks[64][136];
  __shared__ ushort Vs[128][72];
  __shared__ ushort Ps[4][16][72];

  bf16x8 qf[4];
  int qrow = qb * 64 + wave * 16 + (lane & 15);
#pragma unroll
  for (int kk = 0; kk < 4; kk++)
    qf[kk] = *(const bf16x8*)&q[(size_t)qrow * DIM + h * HD + kk * 32 + (lane >> 4) * 8];

  f32x4 oacc[8] = {};
  float mrow[4], lrow[4];
  int qr[4];
#pragma unroll
  for (int j = 0; j < 4; j++) {
    mrow[j] = -INFINITY; lrow[j] = 0.f;
    qr[j] = qb * 64 + wave * 16 + (lane >> 4) * 4 + j;
  }

  for (int kt = 0; kt <= qb; kt++) {
    int key0 = kt * 64;
#pragma unroll
    for (int c = 0; c < 4; c++) {
      int e = tid * 32 + c * 8;
      int r = e >> 7, cc = e & 127;
      *(bf16x8*)&Ks[r][cc] =
          *(const bf16x8*)&k[(size_t)(key0 + r) * (NKVH * HD) + kvh * HD + cc];
      int r2 = e >> 6, cc2 = e & 63;
      *(bf16x8*)&Vs[r2][cc2] =
          *(const bf16x8*)&vt[(size_t)(kvh * HD + r2) * SEQ + key0 + cc2];
    }
    __syncthreads();

    f32x4 sf[4] = {};
#pragma unroll
    for (int fn = 0; fn < 4; fn++)
#pragma unroll
      for (int kk = 0; kk < 4; kk++) {
        bf16x8 kf = *(const bf16x8*)&Ks[fn * 16 + (lane & 15)][kk * 32 + (lane >> 4) * 8];
        sf[fn] = __builtin_amdgcn_mfma_f32_16x16x32_bf16(qf[kk], kf, sf[fn], 0, 0, 0);
      }

#pragma unroll
    for (int fn = 0; fn < 4; fn++) {
      int key = key0 + fn * 16 + (lane & 15);
#pragma unroll
      for (int j = 0; j < 4; j++)
        if (key > qr[j]) sf[fn][j] = -INFINITY;
    }

#pragma unroll
    for (int j = 0; j < 4; j++) {
      float mx = fmaxf(fmaxf(sf[0][j], sf[1][j]), fmaxf(sf[2][j], sf[3][j]));
#pragma unroll
      for (int off = 1; off < 16; off <<= 1) mx = fmaxf(mx, __shfl_xor(mx, off));
      float mnew = fmaxf(mrow[j], mx);
      float sc = __expf(mrow[j] - mnew);
      mrow[j] = mnew;
      float rs = 0.f;
#pragma unroll
      for (int fn = 0; fn < 4; fn++) {
        float p = __expf(sf[fn][j] - mnew);
        sf[fn][j] = p;
        rs += p;
      }
#pragma unroll
      for (int off = 1; off < 16; off <<= 1) rs += __shfl_xor(rs, off);
      lrow[j] = lrow[j] * sc + rs;
#pragma unroll
      for (int f2 = 0; f2 < 8; f2++) oacc[f2][j] *= sc;
    }

#pragma unroll
    for (int fn = 0; fn < 4; fn++)
#pragma unroll
      for (int j = 0; j < 4; j++)
        Ps[wave][(lane >> 4) * 4 + j][fn * 16 + (lane & 15)] = f2bf(sf[fn][j]);

#pragma unroll
    for (int kk = 0; kk < 2; kk++) {
      bf16x8 pf = *(const bf16x8*)&Ps[wave][lane & 15][kk * 32 + (lane >> 4) * 8];
#pragma unroll
      for (int f2 = 0; f2 < 8; f2++) {
        bf16x8 vf = *(const bf16x8*)&Vs[f2 * 16 + (lane & 15)][kk * 32 + (lane >> 4) * 8];
        oacc[f2] = __builtin_amdgcn_mfma_f32_16x16x32_bf16(pf, vf, oacc[f2], 0, 0, 0);
      }
    }
    __syncthreads();
  }

#pragma unroll
  for (int j = 0; j < 4; j++) {
    float inv = 1.f / lrow[j];
#pragma unroll
    for (int f2 = 0; f2 < 8; f2++)
      o[(size_t)qr[j] * DIM + h * HD + f2 * 16 + (lane & 15)] = f2bf(oacc[f2][j] * inv);
  }
}

extern "C" void kernel_launch(void* const* d_in, const int* in_sizes, int n_in,
                              void* d_out, int out_size, void* d_ws, size_t ws_size,
                              hipStream_t stream) {
  const float* x    = (const float*)d_in[0];
  const float* w1   = (const float*)d_in[1];
  const float* w2   = (const float*)d_in[2];
  const float* cosT = (const float*)d_in[3];
  const float* sinT = (const float*)d_in[4];
  const float* wq = (const float*)d_in[6];
  const float* la_q = (const float*)d_in[7];
  const float* lb_q = (const float*)d_in[8];
  const float* wk = (const float*)d_in[9];
  const float* la_k = (const float*)d_in[10];
  const float* lb_k = (const float*)d_in[11];
  const float* wv = (const float*)d_in[12];
  const float* la_v = (const float*)d_in[13];
  const float* lb_v = (const float*)d_in[14];
  const float* wo = (const float*)d_in[15];
  const float* la_o = (const float*)d_in[16];
  const float* lb_o = (const float*)d_in[17];
  const float* wg = (const float*)d_in[18];
  const float* la_g = (const float*)d_in[19];
  const float* lb_g = (const float*)d_in[20];
  const float* wu = (const float*)d_in[21];
  const float* la_u = (const float*)d_in[22];
  const float* lb_u = (const float*)d_in[23];
  const float* wd = (const float*)d_in[24];
  const float* la_d = (const float*)d_in[25];
  const float* lb_d = (const float*)d_in[26];
  float* out = (float*)d_out;

  char* ws = (char*)d_ws;
  ushort* xn1 = (ushort*)ws;  ws += (size_t)SEQ * DIM * 2;
  ushort* qb  = (ushort*)ws;  ws += (size_t)SEQ * DIM * 2;
  ushort* kb  = (ushort*)ws;  ws += (size_t)SEQ * NKVH * HD * 2;
  ushort* vtb = (ushort*)ws;  ws += (size_t)SEQ * NKVH * HD * 2;
  ushort* ob  = (ushort*)ws;  ws += (size_t)SEQ * DIM * 2;
  float*  xmed= (float*)ws;   ws += (size_t)SEQ * DIM * 4;
  ushort* xn2 = (ushort*)ws;  ws += (size_t)SEQ * DIM * 2;
  ushort* gate= (ushort*)ws;  ws += (size_t)SEQ * FF * 2;
  ushort* up  = (ushort*)ws;  ws += (size_t)SEQ * FF * 2;   // unused (kept for layout)
  ushort* hb  = (ushort*)ws;  ws += (size_t)SEQ * FF * 2;
  ushort* t_q = (ushort*)ws; ws += SEQ * LR * 2;
  ushort* t_k = (ushort*)ws; ws += SEQ * LR * 2;
  ushort* t_v = (ushort*)ws; ws += SEQ * LR * 2;
  ushort* t_o = (ushort*)ws; ws += SEQ * LR * 2;
  ushort* t_g = (ushort*)ws; ws += SEQ * LR * 2;
  ushort* t_u = (ushort*)ws; ws += SEQ * LR * 2;
  ushort* t_d = (ushort*)ws; ws += SEQ * LR * 2;
  (void)up;

  float* pbuf1 = (float*)gate;  // QKV / wo partials: gate..hb dead then
  float* pbuf2 = (float*)xn2;   // wd partials: xn2+gate+up dead then

  size_t snd = (size_t)SEQ * DIM;

  // 1) norm + fused lora-A (q,k,v share xn1)
  rmsnorm_kernel<<<SEQ, 256, 0, stream>>>(x, w1, xn1);
  lora_a_kernel<3><<<SEQ, 256, 0, stream>>>(xn1, la_q, la_k, la_v, t_q, t_k, t_v, DIM);

  // 2) fused QKV GEMM (split-K2, fused dequant) -> reduce + fused RoPE + V-transpose
  gemm256_kernel<3><<<dim3((DIM + 2048) / 256, SEQ / 256, 2), 512, 0, stream>>>(
      xn1, wq, wk, wv, lb_q, lb_k, lb_v, t_q, t_k, t_v, nullptr, DIM, DIM + 1024,
      pbuf1, SEQ, DIM + 2048, DIM, 32);
  reduce2_qkv_rope<<<SEQ * 896 / 256, 256, 0, stream>>>(pbuf1, cosT, sinT, qb, kb, vtb);

  // 3) attention
  attn_kernel<<<dim3(SEQ / 64, NH), 256, 0, stream>>>(qb, kb, vtb, ob);

  // 4) WO (split-K4, fused dequant) + residual + fused RMSNorm -> xmed, xn2
  lora_a_kernel<1><<<SEQ, 256, 0, stream>>>(ob, la_o, la_o, la_o, t_o, t_o, t_o, DIM);
  gemm256_kernel<3><<<dim3(DIM / 256, SEQ / 256, 4), 512, 0, stream>>>(
      ob, wo, wo, wo, lb_o, lb_o, lb_o, t_o, t_o, t_o, nullptr, DIM, DIM,
      pbuf1, SEQ, DIM, DIM, 16);
  reduce4_res_rms<<<SEQ, 256, 0, stream>>>(pbuf1, x, w2, xmed, xn2, snd);

  // 5) FFN (g,u share xn2); silu fused into wu epilogue
  lora_a_kernel<2><<<SEQ, 256, 0, stream>>>(xn2, la_g, la_u, la_u, t_g, t_u, t_u, DIM);
  gemm256_kernel<0><<<dim3(FF / 256, SEQ / 256, 1), 512, 0, stream>>>(
      xn2, wg, wg, wg, lb_g, lb_g, lb_g, t_g, t_g, t_g, nullptr, FF, FF,
      gate, SEQ, FF, DIM, DIM / 64);
  gemm256_kernel<4><<<dim3(FF / 256, SEQ / 256, 1), 512, 0, stream>>>(
      xn2, wu, wu, wu, lb_u, lb_u, lb_u, t_u, t_u, t_u, gate, FF, FF,
      hb, SEQ, FF, DIM, DIM / 64);
  lora_a_kernel<1><<<SEQ, 256, 0, stream>>>(hb, la_d, la_d, la_d, t_d, t_d, t_d, FF);
  gemm256_kernel<3><<<dim3(DIM / 256, SEQ / 256, 4), 512, 0, stream>>>(
      hb, wd, wd, wd, lb_d, lb_d, lb_d, t_d, t_d, t_d, nullptr, DIM, DIM,
      pbuf2, SEQ, DIM, FF, FF / 4 / 64);
  reduce4_res_kernel<<<snd / 1024, 256, 0, stream>>>(pbuf2, xmed, out, snd);
}

// Round 17
// 925.400 us; speedup vs baseline: 5.3339x; 5.3339x over previous
//
#include <hip/hip_runtime.h>
#include <hip/hip_bf16.h>
#include <math.h>

#define SEQ 1024
#define DIM 4096
#define NH 32
#define HD 128
#define NKVH 8
#define FF 14336
#define LR 16

typedef __attribute__((ext_vector_type(8))) short bf16x8;
typedef __attribute__((ext_vector_type(4))) float f32x4;
typedef __attribute__((ext_vector_type(4))) ushort ushort4v;
typedef __attribute__((ext_vector_type(4))) unsigned int u32x4;

__device__ __forceinline__ ushort f2bf(float f) {
  union { float f; unsigned u; } v; v.f = f;
  unsigned r = (v.u + 0x7FFFu + ((v.u >> 16) & 1u)) >> 16;
  return (ushort)r;
}
__device__ __forceinline__ float bf2f(ushort h) {
  union { unsigned u; float f; } v; v.u = ((unsigned)h) << 16;
  return v.f;
}
__device__ __forceinline__ unsigned cvtpk(float a, float b) {
  unsigned r;
  asm("v_cvt_pk_bf16_f32 %0, %1, %2" : "=v"(r) : "v"(a), "v"(b));
  return r;
}

__device__ __forceinline__ void gload_lds16(const void* g, void* l) {
  __builtin_amdgcn_global_load_lds(
      (const __attribute__((address_space(1))) void*)g,
      (__attribute__((address_space(3))) void*)l, 16, 0, 0);
}

// ---------------- RMSNorm: f32 in -> bf16 out ----------------
__global__ __launch_bounds__(256) void rmsnorm_kernel(const float* __restrict__ x,
                                                      const float* __restrict__ w,
                                                      ushort* __restrict__ out) {
  int row = blockIdx.x;
  int tid = threadIdx.x;
  const float* xr = x + (size_t)row * DIM;
  float vals[16];
  float s = 0.f;
#pragma unroll
  for (int c = 0; c < 4; c++) {
    float4 v = *(const float4*)&xr[(tid + c * 256) * 4];
    vals[c * 4 + 0] = v.x; vals[c * 4 + 1] = v.y;
    vals[c * 4 + 2] = v.z; vals[c * 4 + 3] = v.w;
    s += v.x * v.x + v.y * v.y + v.z * v.z + v.w * v.w;
  }
#pragma unroll
  for (int off = 32; off >= 1; off >>= 1) s += __shfl_down(s, off);
  __shared__ float wsum[4];
  __shared__ float scale_s;
  int lane = tid & 63, wv = tid >> 6;
  if (lane == 0) wsum[wv] = s;
  __syncthreads();
  if (tid == 0) {
    float t = wsum[0] + wsum[1] + wsum[2] + wsum[3];
    scale_s = rsqrtf(t / (float)DIM + 1e-5f);
  }
  __syncthreads();
  float scale = scale_s;
  ushort* orow = out + (size_t)row * DIM;
#pragma unroll
  for (int c = 0; c < 4; c++) {
    int base = (tid + c * 256) * 4;
    float4 wv4 = *(const float4*)&w[base];
    ushort4v ov;
    ov.x = f2bf(vals[c * 4 + 0] * scale * wv4.x);
    ov.y = f2bf(vals[c * 4 + 1] * scale * wv4.y);
    ov.z = f2bf(vals[c * 4 + 2] * scale * wv4.z);
    ov.w = f2bf(vals[c * 4 + 3] * scale * wv4.w);
    *(ushort4v*)&orow[base] = ov;
  }
}

// ---------------- LoRA A: t_l[m][16] = A[m] @ la_l, one row per block ----------------
template <int NL>
__global__ __launch_bounds__(256) void lora_a_kernel(
    const ushort* __restrict__ A,
    const float* __restrict__ la0, const float* __restrict__ la1,
    const float* __restrict__ la2,
    ushort* __restrict__ t0, ushort* __restrict__ t1, ushort* __restrict__ t2,
    int K) {
  int m = blockIdx.x, i = threadIdx.x;
  float acc[NL][16];
#pragma unroll
  for (int l = 0; l < NL; l++)
#pragma unroll
    for (int n = 0; n < 16; n++) acc[l][n] = 0.f;

  const ushort* Arow = A + (size_t)m * K;
  int nc = K >> 8;
  for (int c = 0; c < nc; c++) {
    int k = c * 256 + i;
    float a = bf2f(Arow[k]);
#pragma unroll
    for (int l = 0; l < NL; l++) {
      const float* lap = (l == 0 ? la0 : (l == 1 ? la1 : la2)) + (size_t)k * 16;
#pragma unroll
      for (int q = 0; q < 4; q++) {
        float4 lv = *(const float4*)&lap[q * 4];
        acc[l][q * 4 + 0] += a * lv.x;
        acc[l][q * 4 + 1] += a * lv.y;
        acc[l][q * 4 + 2] += a * lv.z;
        acc[l][q * 4 + 3] += a * lv.w;
      }
    }
  }

  __shared__ float red[256][17];
  __shared__ float red2[16][17];
#pragma unroll
  for (int l = 0; l < NL; l++) {
    __syncthreads();
#pragma unroll
    for (int n = 0; n < 16; n++) red[i][n] = acc[l][n];
    __syncthreads();
    {
      int g = i >> 4, n = i & 15;
      float s = 0.f;
#pragma unroll
      for (int j = 0; j < 16; j++) s += red[g * 16 + j][n];
      red2[g][n] = s;
    }
    __syncthreads();
    if (i < 16) {
      float s2 = 0.f;
#pragma unroll
      for (int g2 = 0; g2 < 16; g2++) s2 += red2[g2][i];
      ushort* tp = (l == 0 ? t0 : (l == 1 ? t1 : t2));
      tp[(size_t)m * LR + i] = f2bf(s2);
    }
  }
}

// ================= 256x256 GEMM, 8 waves, SINGLE-BUFFER LDS (64KB -> 2 blocks/CU) =================
// No min-waves launch bound (round-16's VGPR-64 spill bug); VGPR ~120 <= 128 so
// LDS (64KB) is the occupancy limiter -> 2 blocks/CU; cross-block TLP covers the
// tile-boundary drain (m114). cvt_pk dequant; panel co-location; XOR swizzle.
// WM 0: bf16 [M][N]; WM 3: f32 partial [z][M][N]; WM 4: bf16 silu(gate)*v
template <int WM>
__global__ __launch_bounds__(512) void gemm256_kernel(
    const ushort* __restrict__ A,
    const float* __restrict__ W0, const float* __restrict__ W1, const float* __restrict__ W2,
    const float* __restrict__ lb0, const float* __restrict__ lb1, const float* __restrict__ lb2,
    const ushort* __restrict__ t0, const ushort* __restrict__ t1, const ushort* __restrict__ t2,
    const ushort* __restrict__ gatep,
    int c1, int c2, void* __restrict__ outp, int M, int N, int K, int nkp) {
  __shared__ __align__(16) ushort As[256 * 64];
  __shared__ __align__(16) ushort Bs[256 * 64];
  int tid = threadIdx.x;
  int lane = tid & 63, wave = tid >> 6;
  int wm = wave >> 2, wn = wave & 3;

  // ---- T1 XCD swizzle + panel-sharer-adjacent decode ----
  int gx = gridDim.x, gy = gridDim.y, gz = gridDim.z;
  int flat = blockIdx.x + gx * (blockIdx.y + gy * blockIdx.z);
  int nwg = gx * gy * gz;
  int q = nwg >> 3, r = nwg & 7;
  int xcd = flat & 7;
  int wgid = (xcd < r ? xcd * (q + 1) : r * (q + 1) + (xcd - r) * q) + (flat >> 3);
  int sh = gy * gz;
  int bx = wgid / sh;
  int rem = wgid - bx * sh;
  int z = rem / gy;
  int by = rem - z * gy;

  int n0 = bx * 256, m0 = by * 256;
  int k0 = z * nkp;

  // segment select (weight + lora)
  const float* Wp; const float* lbp; const ushort* tp; int nseg, wseg;
  if (n0 < c1)      { Wp = W0; lbp = lb0; tp = t0; nseg = n0;      wseg = c1; }
  else if (n0 < c2) { Wp = W1; lbp = lb1; tp = t1; nseg = n0 - c1; wseg = c2 - c1; }
  else              { Wp = W2; lbp = lb2; tp = t2; nseg = n0 - c2; wseg = N - c2; }

  // A staging
  int srow = tid >> 3;
  int sswz = ((tid & 7) ^ (srow & 7)) * 8;
  const ushort* Ab = A + (size_t)(m0 + srow) * K + sswz;
  // B reg-staging source (linear; swizzle at ds_write)
  const float* Wbase = Wp + (size_t)(nseg + srow) * K + (tid & 7) * 8;

  f32x4 acc[8][4] = {};
  float4 breg[8];

#define SHALF_A(kt, h)                                                        \
  _Pragma("unroll") for (int i = 2 * (h); i < 2 * (h) + 2; i++) {             \
    gload_lds16(Ab + (size_t)(i * 64) * K + (size_t)(kt) * 64,                \
                &As[wave * 512 + i * 4096]);                                  \
  }
#define BLOAD(kt, h)                                                          \
  {                                                                           \
    const float* gp = Wbase + (size_t)((h) * 128) * K + (size_t)(kt) * 64;    \
    breg[(h) * 4 + 0] = *(const float4*)gp;                                   \
    breg[(h) * 4 + 1] = *(const float4*)(gp + 4);                             \
    breg[(h) * 4 + 2] = *(const float4*)(gp + (size_t)64 * K);                \
    breg[(h) * 4 + 3] = *(const float4*)(gp + (size_t)64 * K + 4);            \
  }
#define WRITE_B()                                                             \
  _Pragma("unroll") for (int h = 0; h < 2; h++)                               \
  _Pragma("unroll") for (int j = 0; j < 2; j++) {                             \
    int rr = h * 128 + j * 64 + srow;                                         \
    float4 lo = breg[h * 4 + j * 2 + 0];                                      \
    float4 hi = breg[h * 4 + j * 2 + 1];                                      \
    u32x4 v;                                                                  \
    v.x = cvtpk(lo.x, lo.y); v.y = cvtpk(lo.z, lo.w);                         \
    v.z = cvtpk(hi.x, hi.y); v.w = cvtpk(hi.z, hi.w);                         \
    *(u32x4*)&Bs[rr * 64 + (((tid & 7) ^ (rr & 7))) * 8] = v;                 \
  }
#define LDFRAG(buf, rr, ks) \
  (*(const bf16x8*)&(buf)[(rr) * 64 + (((ks) * 4 + (lane >> 4)) ^ ((rr) & 7)) * 8])

  // ---- prologue: stage tile 0 ----
  BLOAD(k0, 0); BLOAD(k0, 1);
  SHALF_A(k0, 0); SHALF_A(k0, 1);
  asm volatile("s_waitcnt vmcnt(4)" ::: "memory");  // B(0) landed; A(0) in flight
  WRITE_B();
  asm volatile("s_waitcnt vmcnt(0) lgkmcnt(0)" ::: "memory");
  __builtin_amdgcn_s_barrier();
  __builtin_amdgcn_sched_barrier(0);

  for (int tau = 0; tau < nkp; tau++) {
    bool s1 = (tau + 1 < nkp);
    // ---- compute: 4 quadrant phases, no barriers (LDS stable); B(tau+1) issued mid-way ----
    bf16x8 bfr[4][2];
#pragma unroll
    for (int p = 0; p < 4; p++) {
      bf16x8 af[2][2];
#pragma unroll
      for (int qq = 0; qq < 2; qq++) {
        int ra = wm * 128 + (p * 2 + qq) * 16 + (lane & 15);
#pragma unroll
        for (int ks = 0; ks < 2; ks++) af[qq][ks] = LDFRAG(As, ra, ks);
      }
      if (p == 0) {
#pragma unroll
        for (int f = 0; f < 4; f++) {
          int rb = wn * 64 + f * 16 + (lane & 15);
#pragma unroll
          for (int ks = 0; ks < 2; ks++) bfr[f][ks] = LDFRAG(Bs, rb, ks);
        }
      }
      if (p == 2 && s1) { BLOAD(k0 + tau + 1, 0); }
      if (p == 3 && s1) { BLOAD(k0 + tau + 1, 1); }
      __builtin_amdgcn_s_setprio(1);
#pragma unroll
      for (int qq = 0; qq < 2; qq++)
#pragma unroll
        for (int fn = 0; fn < 4; fn++)
#pragma unroll
          for (int ks = 0; ks < 2; ks++)
            acc[p * 2 + qq][fn] = __builtin_amdgcn_mfma_f32_16x16x32_bf16(
                af[qq][ks], bfr[fn][ks], acc[p * 2 + qq][fn], 0, 0, 0);
      __builtin_amdgcn_s_setprio(0);
    }
    // ---- tile boundary: all waves done reading; restage ----
    __builtin_amdgcn_sched_barrier(0);
    __builtin_amdgcn_s_barrier();
    if (s1) {
      SHALF_A(k0 + tau + 1, 0); SHALF_A(k0 + tau + 1, 1);
      asm volatile("s_waitcnt vmcnt(4)" ::: "memory");  // B(tau+1) regs landed; A in flight
      WRITE_B();
      asm volatile("s_waitcnt vmcnt(0) lgkmcnt(0)" ::: "memory");
    }
    __builtin_amdgcn_s_barrier();
    __builtin_amdgcn_sched_barrier(0);
  }
#undef SHALF_A
#undef BLOAD
#undef WRITE_B

  // ---- LoRA K-extension (split 0 only) ----
  if (z == 0) {
#pragma unroll
    for (int it = 0; it < 2; it++) {
      int task = tid + it * 512;
      int rr = task >> 2, ls = task & 3;
      int ph = ls ^ (rr & 7);
      bf16x8 avv = {};
      bf16x8 bvv = {};
      if (ls < 2) {
        avv = *(const bf16x8*)&tp[(size_t)(m0 + rr) * LR + ls * 8];
#pragma unroll
        for (int j = 0; j < 8; j++)
          bvv[j] = (short)f2bf(lbp[(size_t)(ls * 8 + j) * wseg + nseg + rr]);
      }
      *(bf16x8*)&As[rr * 64 + ph * 8] = avv;
      *(bf16x8*)&Bs[rr * 64 + ph * 8] = bvv;
    }
    __syncthreads();
    bf16x8 af[8], bfr[4];
#pragma unroll
    for (int f = 0; f < 8; f++) {
      int ra = wm * 128 + f * 16 + (lane & 15);
      af[f] = LDFRAG(As, ra, 0);
    }
#pragma unroll
    for (int f = 0; f < 4; f++) {
      int rb = wn * 64 + f * 16 + (lane & 15);
      bfr[f] = LDFRAG(Bs, rb, 0);
    }
#pragma unroll
    for (int fm = 0; fm < 8; fm++)
#pragma unroll
      for (int fn = 0; fn < 4; fn++)
        acc[fm][fn] = __builtin_amdgcn_mfma_f32_16x16x32_bf16(af[fm], bfr[fn], acc[fm][fn], 0, 0, 0);
  }
#undef LDFRAG

  // ---- write ----
#pragma unroll
  for (int fm = 0; fm < 8; fm++) {
#pragma unroll
    for (int j = 0; j < 4; j++) {
      int mg = m0 + wm * 128 + fm * 16 + (lane >> 4) * 4 + j;
#pragma unroll
      for (int fn = 0; fn < 4; fn++) {
        int ng = n0 + wn * 64 + fn * 16 + (lane & 15);
        float v = acc[fm][fn][j];
        if (WM == 0) {
          ((ushort*)outp)[(size_t)mg * N + ng] = f2bf(v);
        } else if (WM == 4) {
          float g = bf2f(gatep[(size_t)mg * N + ng]);
          float sv = g / (1.f + __expf(-g));
          ((ushort*)outp)[(size_t)mg * N + ng] = f2bf(sv * v);
        } else {
          ((float*)outp)[((size_t)z * M + mg) * (size_t)N + ng] = v;
        }
      }
    }
  }
}

// ---------------- QKV reduce + fused RoPE (q scaled) + V transpose ----------------
__global__ __launch_bounds__(256) void reduce2_qkv_rope(const float* __restrict__ p,
                                                        const float* __restrict__ ct,
                                                        const float* __restrict__ st,
                                                        ushort* __restrict__ qb,
                                                        ushort* __restrict__ kb,
                                                        ushort* __restrict__ vtb) {
  int gidx = blockIdx.x * 256 + threadIdx.x;
  int r = gidx / 896, j = gidx - r * 896;
  size_t row = (size_t)r * 6144;
  size_t sstride = (size_t)SEQ * 6144;
  if (j < 640) {
    bool isq = j < 512;
    int jj = isq ? j : j - 512;
    int h = jj >> 4, d0 = (jj & 15) * 4;
    size_t base = row + (isq ? 0 : DIM) + h * 128 + d0;
    float4 a1 = *(const float4*)&p[base];
    float4 b1 = *(const float4*)&p[base + sstride];
    float4 a2 = *(const float4*)&p[base + 64];
    float4 b2 = *(const float4*)&p[base + 64 + sstride];
    float4 x1, x2;
    x1.x = a1.x + b1.x; x1.y = a1.y + b1.y; x1.z = a1.z + b1.z; x1.w = a1.w + b1.w;
    x2.x = a2.x + b2.x; x2.y = a2.y + b2.y; x2.z = a2.z + b2.z; x2.w = a2.w + b2.w;
    float4 c = *(const float4*)&ct[r * HD + d0];
    float4 s = *(const float4*)&st[r * HD + d0];
    float sc = isq ? 0.08838834764831845f : 1.0f;
    ushort4v o1, o2;
    o1.x = f2bf((x1.x * c.x - x2.x * s.x) * sc);
    o1.y = f2bf((x1.y * c.y - x2.y * s.y) * sc);
    o1.z = f2bf((x1.z * c.z - x2.z * s.z) * sc);
    o1.w = f2bf((x1.w * c.w - x2.w * s.w) * sc);
    o2.x = f2bf((x2.x * c.x + x1.x * s.x) * sc);
    o2.y = f2bf((x2.y * c.y + x1.y * s.y) * sc);
    o2.z = f2bf((x2.z * c.z + x1.z * s.z) * sc);
    o2.w = f2bf((x2.w * c.w + x1.w * s.w) * sc);
    if (isq) {
      *(ushort4v*)&qb[(size_t)r * DIM + h * 128 + d0] = o1;
      *(ushort4v*)&qb[(size_t)r * DIM + h * 128 + d0 + 64] = o2;
    } else {
      *(ushort4v*)&kb[(size_t)r * 1024 + h * 128 + d0] = o1;
      *(ushort4v*)&kb[(size_t)r * 1024 + h * 128 + d0 + 64] = o2;
    }
  } else {
    int jj = j - 640;
    int c0 = jj * 4;
    size_t base = row + DIM + 1024 + c0;
    float4 a = *(const float4*)&p[base];
    float4 b = *(const float4*)&p[base + sstride];
    vtb[(size_t)(c0 + 0) * SEQ + r] = f2bf(a.x + b.x);
    vtb[(size_t)(c0 + 1) * SEQ + r] = f2bf(a.y + b.y);
    vtb[(size_t)(c0 + 2) * SEQ + r] = f2bf(a.z + b.z);
    vtb[(size_t)(c0 + 3) * SEQ + r] = f2bf(a.w + b.w);
  }
}

// ---------------- split-K reduce + residual -> f32 out ----------------
__global__ __launch_bounds__(256) void reduce4_res_kernel(const float* __restrict__ p,
                                                          const float* __restrict__ res,
                                                          float* __restrict__ out,
                                                          size_t sstride) {
  size_t i = ((size_t)blockIdx.x * 256 + threadIdx.x) * 4;
  float4 a = *(const float4*)&p[i];
  float4 b = *(const float4*)&p[i + sstride];
  float4 c = *(const float4*)&p[i + 2 * sstride];
  float4 d = *(const float4*)&p[i + 3 * sstride];
  float4 r = *(const float4*)&res[i];
  float4 o;
  o.x = a.x + b.x + c.x + d.x + r.x;
  o.y = a.y + b.y + c.y + d.y + r.y;
  o.z = a.z + b.z + c.z + d.z + r.z;
  o.w = a.w + b.w + c.w + d.w + r.w;
  *(float4*)&out[i] = o;
}

// ---------------- split-K reduce + residual + fused RMSNorm (one row/block) ----------------
__global__ __launch_bounds__(256) void reduce4_res_rms(const float* __restrict__ p,
                                                       const float* __restrict__ res,
                                                       const float* __restrict__ w,
                                                       float* __restrict__ xmed,
                                                       ushort* __restrict__ xn2,
                                                       size_t sstride) {
  int row = blockIdx.x, tid = threadIdx.x;
  size_t base = (size_t)row * DIM;
  float vals[16];
  float sq = 0.f;
#pragma unroll
  for (int c = 0; c < 4; c++) {
    size_t i = base + (tid + c * 256) * 4;
    float4 a = *(const float4*)&p[i];
    float4 b = *(const float4*)&p[i + sstride];
    float4 cc = *(const float4*)&p[i + 2 * sstride];
    float4 d = *(const float4*)&p[i + 3 * sstride];
    float4 r = *(const float4*)&res[i];
    float4 v;
    v.x = a.x + b.x + cc.x + d.x + r.x;
    v.y = a.y + b.y + cc.y + d.y + r.y;
    v.z = a.z + b.z + cc.z + d.z + r.z;
    v.w = a.w + b.w + cc.w + d.w + r.w;
    *(float4*)&xmed[i] = v;
    vals[c * 4 + 0] = v.x; vals[c * 4 + 1] = v.y;
    vals[c * 4 + 2] = v.z; vals[c * 4 + 3] = v.w;
    sq += v.x * v.x + v.y * v.y + v.z * v.z + v.w * v.w;
  }
#pragma unroll
  for (int off = 32; off >= 1; off >>= 1) sq += __shfl_down(sq, off);
  __shared__ float wsum[4];
  __shared__ float scale_s;
  int lane = tid & 63, wv = tid >> 6;
  if (lane == 0) wsum[wv] = sq;
  __syncthreads();
  if (tid == 0) {
    float t = wsum[0] + wsum[1] + wsum[2] + wsum[3];
    scale_s = rsqrtf(t / (float)DIM + 1e-5f);
  }
  __syncthreads();
  float scale = scale_s;
#pragma unroll
  for (int c = 0; c < 4; c++) {
    int off = (tid + c * 256) * 4;
    float4 wv4 = *(const float4*)&w[off];
    ushort4v ov;
    ov.x = f2bf(vals[c * 4 + 0] * scale * wv4.x);
    ov.y = f2bf(vals[c * 4 + 1] * scale * wv4.y);
    ov.z = f2bf(vals[c * 4 + 2] * scale * wv4.z);
    ov.w = f2bf(vals[c * 4 + 3] * scale * wv4.w);
    *(ushort4v*)&xn2[base + off] = ov;
  }
}

// ---------------- Flash attention (causal, GQA 4:1), kvh-XCD co-located, LPT order ----------------
__global__ __launch_bounds__(256) void attn_kernel(const ushort* __restrict__ q,
                                                   const ushort* __restrict__ k,
                                                   const ushort* __restrict__ vt,
                                                   ushort* __restrict__ o) {
  int flat = blockIdx.x + 16 * blockIdx.y;  // 0..511
  int kvh = flat & 7;
  int idx = flat >> 3;
  int h = kvh * 4 + (idx & 3);
  int qb = 15 - (idx >> 2);                 // descending work order
  int tid = threadIdx.x, lane = tid & 63, wave = tid >> 6;
  __shared__ ushort Ks[64][136];
  __shared__ ushort Vs[128][72];
  __shared__ ushort Ps[4][16][72];

  bf16x8 qf[4];
  int qrow = qb * 64 + wave * 16 + (lane & 15);
#pragma unroll
  for (int kk = 0; kk < 4; kk++)
    qf[kk] = *(const bf16x8*)&q[(size_t)qrow * DIM + h * HD + kk * 32 + (lane >> 4) * 8];

  f32x4 oacc[8] = {};
  float mrow[4], lrow[4];
  int qr[4];
#pragma unroll
  for (int j = 0; j < 4; j++) {
    mrow[j] = -INFINITY; lrow[j] = 0.f;
    qr[j] = qb * 64 + wave * 16 + (lane >> 4) * 4 + j;
  }

  for (int kt = 0; kt <= qb; kt++) {
    int key0 = kt * 64;
#pragma unroll
    for (int c = 0; c < 4; c++) {
      int e = tid * 32 + c * 8;
      int r = e >> 7, cc = e & 127;
      *(bf16x8*)&Ks[r][cc] =
          *(const bf16x8*)&k[(size_t)(key0 + r) * (NKVH * HD) + kvh * HD + cc];
      int r2 = e >> 6, cc2 = e & 63;
      *(bf16x8*)&Vs[r2][cc2] =
          *(const bf16x8*)&vt[(size_t)(kvh * HD + r2) * SEQ + key0 + cc2];
    }
    __syncthreads();

    f32x4 sf[4] = {};
#pragma unroll
    for (int fn = 0; fn < 4; fn++)
#pragma unroll
      for (int kk = 0; kk < 4; kk++) {
        bf16x8 kf = *(const bf16x8*)&Ks[fn * 16 + (lane & 15)][kk * 32 + (lane >> 4) * 8];
        sf[fn] = __builtin_amdgcn_mfma_f32_16x16x32_bf16(qf[kk], kf, sf[fn], 0, 0, 0);
      }

#pragma unroll
    for (int fn = 0; fn < 4; fn++) {
      int key = key0 + fn * 16 + (lane & 15);
#pragma unroll
      for (int j = 0; j < 4; j++)
        if (key > qr[j]) sf[fn][j] = -INFINITY;
    }

#pragma unroll
    for (int j = 0; j < 4; j++) {
      float mx = fmaxf(fmaxf(sf[0][j], sf[1][j]), fmaxf(sf[2][j], sf[3][j]));
#pragma unroll
      for (int off = 1; off < 16; off <<= 1) mx = fmaxf(mx, __shfl_xor(mx, off));
      float mnew = fmaxf(mrow[j], mx);
      float sc = __expf(mrow[j] - mnew);
      mrow[j] = mnew;
      float rs = 0.f;
#pragma unroll
      for (int fn = 0; fn < 4; fn++) {
        float p = __expf(sf[fn][j] - mnew);
        sf[fn][j] = p;
        rs += p;
      }
#pragma unroll
      for (int off = 1; off < 16; off <<= 1) rs += __shfl_xor(rs, off);
      lrow[j] = lrow[j] * sc + rs;
#pragma unroll
      for (int f2 = 0; f2 < 8; f2++) oacc[f2][j] *= sc;
    }

#pragma unroll
    for (int fn = 0; fn < 4; fn++)
#pragma unroll
      for (int j = 0; j < 4; j++)
        Ps[wave][(lane >> 4) * 4 + j][fn * 16 + (lane & 15)] = f2bf(sf[fn][j]);

#pragma unroll
    for (int kk = 0; kk < 2; kk++) {
      bf16x8 pf = *(const bf16x8*)&Ps[wave][lane & 15][kk * 32 + (lane >> 4) * 8];
#pragma unroll
      for (int f2 = 0; f2 < 8; f2++) {
        bf16x8 vf = *(const bf16x8*)&Vs[f2 * 16 + (lane & 15)][kk * 32 + (lane >> 4) * 8];
        oacc[f2] = __builtin_amdgcn_mfma_f32_16x16x32_bf16(pf, vf, oacc[f2], 0, 0, 0);
      }
    }
    __syncthreads();
  }

#pragma unroll
  for (int j = 0; j < 4; j++) {
    float inv = 1.f / lrow[j];
#pragma unroll
    for (int f2 = 0; f2 < 8; f2++)
      o[(size_t)qr[j] * DIM + h * HD + f2 * 16 + (lane & 15)] = f2bf(oacc[f2][j] * inv);
  }
}

extern "C" void kernel_launch(void* const* d_in, const int* in_sizes, int n_in,
                              void* d_out, int out_size, void* d_ws, size_t ws_size,
                              hipStream_t stream) {
  const float* x    = (const float*)d_in[0];
  const float* w1   = (const float*)d_in[1];
  const float* w2   = (const float*)d_in[2];
  const float* cosT = (const float*)d_in[3];
  const float* sinT = (const float*)d_in[4];
  const float* wq = (const float*)d_in[6];
  const float* la_q = (const float*)d_in[7];
  const float* lb_q = (const float*)d_in[8];
  const float* wk = (const float*)d_in[9];
  const float* la_k = (const float*)d_in[10];
  const float* lb_k = (const float*)d_in[11];
  const float* wv = (const float*)d_in[12];
  const float* la_v = (const float*)d_in[13];
  const float* lb_v = (const float*)d_in[14];
  const float* wo = (const float*)d_in[15];
  const float* la_o = (const float*)d_in[16];
  const float* lb_o = (const float*)d_in[17];
  const float* wg = (const float*)d_in[18];
  const float* la_g = (const float*)d_in[19];
  const float* lb_g = (const float*)d_in[20];
  const float* wu = (const float*)d_in[21];
  const float* la_u = (const float*)d_in[22];
  const float* lb_u = (const float*)d_in[23];
  const float* wd = (const float*)d_in[24];
  const float* la_d = (const float*)d_in[25];
  const float* lb_d = (const float*)d_in[26];
  float* out = (float*)d_out;

  char* ws = (char*)d_ws;
  ushort* xn1 = (ushort*)ws;  ws += (size_t)SEQ * DIM * 2;
  ushort* qb  = (ushort*)ws;  ws += (size_t)SEQ * DIM * 2;
  ushort* kb  = (ushort*)ws;  ws += (size_t)SEQ * NKVH * HD * 2;
  ushort* vtb = (ushort*)ws;  ws += (size_t)SEQ * NKVH * HD * 2;
  ushort* ob  = (ushort*)ws;  ws += (size_t)SEQ * DIM * 2;
  float*  xmed= (float*)ws;   ws += (size_t)SEQ * DIM * 4;
  ushort* xn2 = (ushort*)ws;  ws += (size_t)SEQ * DIM * 2;
  ushort* gate= (ushort*)ws;  ws += (size_t)SEQ * FF * 2;
  ushort* up  = (ushort*)ws;  ws += (size_t)SEQ * FF * 2;   // unused (kept for layout)
  ushort* hb  = (ushort*)ws;  ws += (size_t)SEQ * FF * 2;
  ushort* t_q = (ushort*)ws; ws += SEQ * LR * 2;
  ushort* t_k = (ushort*)ws; ws += SEQ * LR * 2;
  ushort* t_v = (ushort*)ws; ws += SEQ * LR * 2;
  ushort* t_o = (ushort*)ws; ws += SEQ * LR * 2;
  ushort* t_g = (ushort*)ws; ws += SEQ * LR * 2;
  ushort* t_u = (ushort*)ws; ws += SEQ * LR * 2;
  ushort* t_d = (ushort*)ws; ws += SEQ * LR * 2;
  (void)up;

  float* pbuf1 = (float*)gate;  // QKV / wo partials: gate..hb dead then
  float* pbuf2 = (float*)xn2;   // wd partials: xn2+gate+up dead then

  size_t snd = (size_t)SEQ * DIM;

  // 1) norm + fused lora-A (q,k,v share xn1)
  rmsnorm_kernel<<<SEQ, 256, 0, stream>>>(x, w1, xn1);
  lora_a_kernel<3><<<SEQ, 256, 0, stream>>>(xn1, la_q, la_k, la_v, t_q, t_k, t_v, DIM);

  // 2) fused QKV GEMM (split-K2, fused dequant) -> reduce + fused RoPE + V-transpose
  gemm256_kernel<3><<<dim3((DIM + 2048) / 256, SEQ / 256, 2), 512, 0, stream>>>(
      xn1, wq, wk, wv, lb_q, lb_k, lb_v, t_q, t_k, t_v, nullptr, DIM, DIM + 1024,
      pbuf1, SEQ, DIM + 2048, DIM, 32);
  reduce2_qkv_rope<<<SEQ * 896 / 256, 256, 0, stream>>>(pbuf1, cosT, sinT, qb, kb, vtb);

  // 3) attention
  attn_kernel<<<dim3(SEQ / 64, NH), 256, 0, stream>>>(qb, kb, vtb, ob);

  // 4) WO (split-K4, fused dequant) + residual + fused RMSNorm -> xmed, xn2
  lora_a_kernel<1><<<SEQ, 256, 0, stream>>>(ob, la_o, la_o, la_o, t_o, t_o, t_o, DIM);
  gemm256_kernel<3><<<dim3(DIM / 256, SEQ / 256, 4), 512, 0, stream>>>(
      ob, wo, wo, wo, lb_o, lb_o, lb_o, t_o, t_o, t_o, nullptr, DIM, DIM,
      pbuf1, SEQ, DIM, DIM, 16);
  reduce4_res_rms<<<SEQ, 256, 0, stream>>>(pbuf1, x, w2, xmed, xn2, snd);

  // 5) FFN (g,u share xn2); silu fused into wu epilogue
  lora_a_kernel<2><<<SEQ, 256, 0, stream>>>(xn2, la_g, la_u, la_u, t_g, t_u, t_u, DIM);
  gemm256_kernel<0><<<dim3(FF / 256, SEQ / 256, 1), 512, 0, stream>>>(
      xn2, wg, wg, wg, lb_g, lb_g, lb_g, t_g, t_g, t_g, nullptr, FF, FF,
      gate, SEQ, FF, DIM, DIM / 64);
  gemm256_kernel<4><<<dim3(FF / 256, SEQ / 256, 1), 512, 0, stream>>>(
      xn2, wu, wu, wu, lb_u, lb_u, lb_u, t_u, t_u, t_u, gate, FF, FF,
      hb, SEQ, FF, DIM, DIM / 64);
  lora_a_kernel<1><<<SEQ, 256, 0, stream>>>(hb, la_d, la_d, la_d, t_d, t_d, t_d, FF);
  gemm256_kernel<3><<<dim3(DIM / 256, SEQ / 256, 4), 512, 0, stream>>>(
      hb, wd, wd, wd, lb_d, lb_d, lb_d, t_d, t_d, t_d, nullptr, DIM, DIM,
      pbuf2, SEQ, DIM, FF, FF / 4 / 64);
  reduce4_res_kernel<<<snd / 1024, 256, 0, stream>>>(pbuf2, xmed, out, snd);
}

// Round 18
// 873.303 us; speedup vs baseline: 5.6521x; 1.0597x over previous
//
#include <hip/hip_runtime.h>
#include <hip/hip_bf16.h>
#include <math.h>

#define SEQ 1024
#define DIM 4096
#define NH 32
#define HD 128
#define NKVH 8
#define FF 14336
#define LR 16

typedef __attribute__((ext_vector_type(8))) short bf16x8;
typedef __attribute__((ext_vector_type(4))) float f32x4;
typedef __attribute__((ext_vector_type(4))) ushort ushort4v;
typedef __attribute__((ext_vector_type(4))) unsigned int u32x4;

__device__ __forceinline__ ushort f2bf(float f) {
  union { float f; unsigned u; } v; v.f = f;
  unsigned r = (v.u + 0x7FFFu + ((v.u >> 16) & 1u)) >> 16;
  return (ushort)r;
}
__device__ __forceinline__ float bf2f(ushort h) {
  union { unsigned u; float f; } v; v.u = ((unsigned)h) << 16;
  return v.f;
}
__device__ __forceinline__ unsigned cvtpk(float a, float b) {
  unsigned r;
  asm("v_cvt_pk_bf16_f32 %0, %1, %2" : "=v"(r) : "v"(a), "v"(b));
  return r;
}

__device__ __forceinline__ void gload_lds16(const void* g, void* l) {
  __builtin_amdgcn_global_load_lds(
      (const __attribute__((address_space(1))) void*)g,
      (__attribute__((address_space(3))) void*)l, 16, 0, 0);
}

// ---------------- RMSNorm: f32 in -> bf16 out ----------------
__global__ __launch_bounds__(256) void rmsnorm_kernel(const float* __restrict__ x,
                                                      const float* __restrict__ w,
                                                      ushort* __restrict__ out) {
  int row = blockIdx.x;
  int tid = threadIdx.x;
  const float* xr = x + (size_t)row * DIM;
  float vals[16];
  float s = 0.f;
#pragma unroll
  for (int c = 0; c < 4; c++) {
    float4 v = *(const float4*)&xr[(tid + c * 256) * 4];
    vals[c * 4 + 0] = v.x; vals[c * 4 + 1] = v.y;
    vals[c * 4 + 2] = v.z; vals[c * 4 + 3] = v.w;
    s += v.x * v.x + v.y * v.y + v.z * v.z + v.w * v.w;
  }
#pragma unroll
  for (int off = 32; off >= 1; off >>= 1) s += __shfl_down(s, off);
  __shared__ float wsum[4];
  __shared__ float scale_s;
  int lane = tid & 63, wv = tid >> 6;
  if (lane == 0) wsum[wv] = s;
  __syncthreads();
  if (tid == 0) {
    float t = wsum[0] + wsum[1] + wsum[2] + wsum[3];
    scale_s = rsqrtf(t / (float)DIM + 1e-5f);
  }
  __syncthreads();
  float scale = scale_s;
  ushort* orow = out + (size_t)row * DIM;
#pragma unroll
  for (int c = 0; c < 4; c++) {
    int base = (tid + c * 256) * 4;
    float4 wv4 = *(const float4*)&w[base];
    ushort4v ov;
    ov.x = f2bf(vals[c * 4 + 0] * scale * wv4.x);
    ov.y = f2bf(vals[c * 4 + 1] * scale * wv4.y);
    ov.z = f2bf(vals[c * 4 + 2] * scale * wv4.z);
    ov.w = f2bf(vals[c * 4 + 3] * scale * wv4.w);
    *(ushort4v*)&orow[base] = ov;
  }
}

// ---------------- LoRA A: t_l[m][16] = A[m] @ la_l, one row per block ----------------
template <int NL>
__global__ __launch_bounds__(256) void lora_a_kernel(
    const ushort* __restrict__ A,
    const float* __restrict__ la0, const float* __restrict__ la1,
    const float* __restrict__ la2,
    ushort* __restrict__ t0, ushort* __restrict__ t1, ushort* __restrict__ t2,
    int K) {
  int m = blockIdx.x, i = threadIdx.x;
  float acc[NL][16];
#pragma unroll
  for (int l = 0; l < NL; l++)
#pragma unroll
    for (int n = 0; n < 16; n++) acc[l][n] = 0.f;

  const ushort* Arow = A + (size_t)m * K;
  int nc = K >> 8;
  for (int c = 0; c < nc; c++) {
    int k = c * 256 + i;
    float a = bf2f(Arow[k]);
#pragma unroll
    for (int l = 0; l < NL; l++) {
      const float* lap = (l == 0 ? la0 : (l == 1 ? la1 : la2)) + (size_t)k * 16;
#pragma unroll
      for (int q = 0; q < 4; q++) {
        float4 lv = *(const float4*)&lap[q * 4];
        acc[l][q * 4 + 0] += a * lv.x;
        acc[l][q * 4 + 1] += a * lv.y;
        acc[l][q * 4 + 2] += a * lv.z;
        acc[l][q * 4 + 3] += a * lv.w;
      }
    }
  }

  __shared__ float red[256][17];
  __shared__ float red2[16][17];
#pragma unroll
  for (int l = 0; l < NL; l++) {
    __syncthreads();
#pragma unroll
    for (int n = 0; n < 16; n++) red[i][n] = acc[l][n];
    __syncthreads();
    {
      int g = i >> 4, n = i & 15;
      float s = 0.f;
#pragma unroll
      for (int j = 0; j < 16; j++) s += red[g * 16 + j][n];
      red2[g][n] = s;
    }
    __syncthreads();
    if (i < 16) {
      float s2 = 0.f;
#pragma unroll
      for (int g2 = 0; g2 < 16; g2++) s2 += red2[g2][i];
      ushort* tp = (l == 0 ? t0 : (l == 1 ? t1 : t2));
      tp[(size_t)m * LR + i] = f2bf(s2);
    }
  }
}

// ================= 256x256 GEMM, 8 waves, 8-phase dbuf (round-15 proven), fused dequant ===========
// 3-segment weight/lora/output select; per-segment bf16 out (WM0, row stride = wseg)
// or f32 split-K partials (WM3). cvt_pk dequant; panel co-location; XOR swizzle.
template <int WM>
__global__ __launch_bounds__(512) void gemm256_kernel(
    const ushort* __restrict__ A,
    const float* __restrict__ W0, const float* __restrict__ W1, const float* __restrict__ W2,
    const float* __restrict__ lb0, const float* __restrict__ lb1, const float* __restrict__ lb2,
    const ushort* __restrict__ t0, const ushort* __restrict__ t1, const ushort* __restrict__ t2,
    void* __restrict__ o0, void* __restrict__ o1, void* __restrict__ o2,
    int c1, int c2, void* __restrict__ outp, int M, int N, int K, int nkp) {
  __shared__ __align__(16) ushort As[2][256 * 64];
  __shared__ __align__(16) ushort Bs[2][256 * 64];
  int tid = threadIdx.x;
  int lane = tid & 63, wave = tid >> 6;
  int wm = wave >> 2, wn = wave & 3;

  // ---- T1 XCD swizzle + panel-sharer-adjacent decode ----
  int gx = gridDim.x, gy = gridDim.y, gz = gridDim.z;
  int flat = blockIdx.x + gx * (blockIdx.y + gy * blockIdx.z);
  int nwg = gx * gy * gz;
  int q = nwg >> 3, r = nwg & 7;
  int xcd = flat & 7;
  int wgid = (xcd < r ? xcd * (q + 1) : r * (q + 1) + (xcd - r) * q) + (flat >> 3);
  int sh = gy * gz;
  int bx = wgid / sh;
  int rem = wgid - bx * sh;
  int z = rem / gy;
  int by = rem - z * gy;

  int n0 = bx * 256, m0 = by * 256;
  int k0 = z * nkp;

  // segment select (weight + lora + out)
  const float* Wp; const float* lbp; const ushort* tp; void* osel; int nseg, wseg;
  if (n0 < c1)      { Wp = W0; lbp = lb0; tp = t0; osel = o0; nseg = n0;      wseg = c1; }
  else if (n0 < c2) { Wp = W1; lbp = lb1; tp = t1; osel = o1; nseg = n0 - c1; wseg = c2 - c1; }
  else              { Wp = W2; lbp = lb2; tp = t2; osel = o2; nseg = n0 - c2; wseg = N - c2; }

  // A staging
  int srow = tid >> 3;
  int sswz = ((tid & 7) ^ (srow & 7)) * 8;
  const ushort* Ab = A + (size_t)(m0 + srow) * K + sswz;
  // B reg-staging source (linear; swizzle at ds_write)
  const float* Wbase = Wp + (size_t)(nseg + srow) * K + (tid & 7) * 8;

  f32x4 acc[8][4] = {};
  float4 breg[8];

#define SHALF(kt, b, h)                                                       \
  _Pragma("unroll") for (int i = 2 * (h); i < 2 * (h) + 2; i++) {             \
    gload_lds16(Ab + (size_t)(i * 64) * K + (size_t)(kt) * 64,                \
                &As[b][wave * 512 + i * 4096]);                               \
  }
#define BLOAD(kt, h)                                                          \
  {                                                                           \
    const float* gp = Wbase + (size_t)((h) * 128) * K + (size_t)(kt) * 64;    \
    breg[(h) * 4 + 0] = *(const float4*)gp;                                   \
    breg[(h) * 4 + 1] = *(const float4*)(gp + 4);                             \
    breg[(h) * 4 + 2] = *(const float4*)(gp + (size_t)64 * K);                \
    breg[(h) * 4 + 3] = *(const float4*)(gp + (size_t)64 * K + 4);            \
  }
#define WRITE_B(b)                                                            \
  _Pragma("unroll") for (int h = 0; h < 2; h++)                               \
  _Pragma("unroll") for (int j = 0; j < 2; j++) {                             \
    int rr = h * 128 + j * 64 + srow;                                         \
    float4 lo = breg[h * 4 + j * 2 + 0];                                      \
    float4 hi = breg[h * 4 + j * 2 + 1];                                      \
    u32x4 v;                                                                  \
    v.x = cvtpk(lo.x, lo.y); v.y = cvtpk(lo.z, lo.w);                         \
    v.z = cvtpk(hi.x, hi.y); v.w = cvtpk(hi.z, hi.w);                         \
    *(u32x4*)&Bs[b][rr * 64 + (((tid & 7) ^ (rr & 7))) * 8] = v;              \
  }
#define LDFRAG(buf, rr, ks) \
  (*(const bf16x8*)&(buf)[(rr) * 64 + (((ks) * 4 + (lane >> 4)) ^ ((rr) & 7)) * 8])

  // ---- prologue ----
  BLOAD(k0, 0); BLOAD(k0, 1);
  SHALF(k0, 0, 0); SHALF(k0, 0, 1);
  asm volatile("s_waitcnt vmcnt(4)" ::: "memory");
  WRITE_B(0);
  if (nkp > 1) { BLOAD(k0 + 1, 0); BLOAD(k0 + 1, 1); }
  if (nkp > 1) asm volatile("s_waitcnt vmcnt(8)" ::: "memory");
  else         asm volatile("s_waitcnt vmcnt(0)" ::: "memory");
  asm volatile("s_waitcnt lgkmcnt(0)" ::: "memory");
  __builtin_amdgcn_s_barrier();
  __builtin_amdgcn_sched_barrier(0);

  for (int tau = 0; tau < nkp; tau++) {
    int b = tau & 1;
    bool s1 = (tau + 1 < nkp), s2 = (tau + 2 < nkp);
    const ushort* as = As[b];
    const ushort* bs = Bs[b];
    bf16x8 bfr[4][2];
#pragma unroll
    for (int p = 0; p < 4; p++) {
      bf16x8 af[2][2];
#pragma unroll
      for (int qq = 0; qq < 2; qq++) {
        int ra = wm * 128 + (p * 2 + qq) * 16 + (lane & 15);
#pragma unroll
        for (int ks = 0; ks < 2; ks++) af[qq][ks] = LDFRAG(as, ra, ks);
      }
      if (p == 0) {
#pragma unroll
        for (int f = 0; f < 4; f++) {
          int rb = wn * 64 + f * 16 + (lane & 15);
#pragma unroll
          for (int ks = 0; ks < 2; ks++) bfr[f][ks] = LDFRAG(bs, rb, ks);
        }
      }
      if (p == 0 && s1) { SHALF(k0 + tau + 1, b ^ 1, 0); }
      if (p == 1 && s1) { SHALF(k0 + tau + 1, b ^ 1, 1); }
      if (p == 2 && s2) { BLOAD(k0 + tau + 2, 0); }
      if (p == 3 && s2) { BLOAD(k0 + tau + 2, 1); }
      __builtin_amdgcn_sched_barrier(0);
      __builtin_amdgcn_s_barrier();
      asm volatile("s_waitcnt lgkmcnt(0)" ::: "memory");
      __builtin_amdgcn_sched_barrier(0);
      __builtin_amdgcn_s_setprio(1);
#pragma unroll
      for (int qq = 0; qq < 2; qq++)
#pragma unroll
        for (int fn = 0; fn < 4; fn++)
#pragma unroll
          for (int ks = 0; ks < 2; ks++)
            acc[p * 2 + qq][fn] = __builtin_amdgcn_mfma_f32_16x16x32_bf16(
                af[qq][ks], bfr[fn][ks], acc[p * 2 + qq][fn], 0, 0, 0);
      __builtin_amdgcn_s_setprio(0);
      __builtin_amdgcn_sched_barrier(0);
      if (p == 1 && s1) {
        asm volatile("s_waitcnt vmcnt(4)" ::: "memory");
        WRITE_B(b ^ 1);
        __builtin_amdgcn_sched_barrier(0);
      }
      if (p == 3) {
        if (s2) asm volatile("s_waitcnt vmcnt(8)" ::: "memory");
        else    asm volatile("s_waitcnt vmcnt(0)" ::: "memory");
      }
      __builtin_amdgcn_s_barrier();
      __builtin_amdgcn_sched_barrier(0);
    }
  }
#undef SHALF
#undef BLOAD
#undef WRITE_B

  // ---- LoRA K-extension (split 0 only) ----
  if (z == 0) {
#pragma unroll
    for (int it = 0; it < 2; it++) {
      int task = tid + it * 512;
      int rr = task >> 2, ls = task & 3;
      int ph = ls ^ (rr & 7);
      bf16x8 avv = {};
      bf16x8 bvv = {};
      if (ls < 2) {
        avv = *(const bf16x8*)&tp[(size_t)(m0 + rr) * LR + ls * 8];
#pragma unroll
        for (int j = 0; j < 8; j++)
          bvv[j] = (short)f2bf(lbp[(size_t)(ls * 8 + j) * wseg + nseg + rr]);
      }
      *(bf16x8*)&As[0][rr * 64 + ph * 8] = avv;
      *(bf16x8*)&Bs[0][rr * 64 + ph * 8] = bvv;
    }
    __syncthreads();
    bf16x8 af[8], bfr[4];
#pragma unroll
    for (int f = 0; f < 8; f++) {
      int ra = wm * 128 + f * 16 + (lane & 15);
      af[f] = LDFRAG(As[0], ra, 0);
    }
#pragma unroll
    for (int f = 0; f < 4; f++) {
      int rb = wn * 64 + f * 16 + (lane & 15);
      bfr[f] = LDFRAG(Bs[0], rb, 0);
    }
#pragma unroll
    for (int fm = 0; fm < 8; fm++)
#pragma unroll
      for (int fn = 0; fn < 4; fn++)
        acc[fm][fn] = __builtin_amdgcn_mfma_f32_16x16x32_bf16(af[fm], bfr[fn], acc[fm][fn], 0, 0, 0);
  }
#undef LDFRAG

  // ---- write ----
#pragma unroll
  for (int fm = 0; fm < 8; fm++) {
#pragma unroll
    for (int j = 0; j < 4; j++) {
      int mg = m0 + wm * 128 + fm * 16 + (lane >> 4) * 4 + j;
#pragma unroll
      for (int fn = 0; fn < 4; fn++) {
        int ncol = wn * 64 + fn * 16 + (lane & 15);  // col within 256-tile
        float v = acc[fm][fn][j];
        if (WM == 0) {
          ((ushort*)osel)[(size_t)mg * wseg + nseg + ncol] = f2bf(v);
        } else {
          ((float*)outp)[((size_t)z * M + mg) * (size_t)N + n0 + ncol] = v;
        }
      }
    }
  }
}

// ---------------- h = silu(gate) * up ----------------
__global__ __launch_bounds__(256) void silu_mul_kernel(const ushort* __restrict__ g,
                                                       const ushort* __restrict__ u,
                                                       ushort* __restrict__ h) {
  size_t idx = (size_t)(blockIdx.x * 256 + threadIdx.x) * 8;
  bf16x8 gv = *(const bf16x8*)&g[idx];
  bf16x8 uv = *(const bf16x8*)&u[idx];
  bf16x8 hv;
#pragma unroll
  for (int i = 0; i < 8; i++) {
    float gf = bf2f((ushort)gv[i]);
    float uf = bf2f((ushort)uv[i]);
    float sv = gf / (1.f + __expf(-gf));
    hv[i] = (short)f2bf(sv * uf);
  }
  *(bf16x8*)&h[idx] = hv;
}

// ---------------- QKV reduce + fused RoPE (q scaled) + V transpose ----------------
__global__ __launch_bounds__(256) void reduce2_qkv_rope(const float* __restrict__ p,
                                                        const float* __restrict__ ct,
                                                        const float* __restrict__ st,
                                                        ushort* __restrict__ qb,
                                                        ushort* __restrict__ kb,
                                                        ushort* __restrict__ vtb) {
  int gidx = blockIdx.x * 256 + threadIdx.x;
  int r = gidx / 896, j = gidx - r * 896;
  size_t row = (size_t)r * 6144;
  size_t sstride = (size_t)SEQ * 6144;
  if (j < 640) {
    bool isq = j < 512;
    int jj = isq ? j : j - 512;
    int h = jj >> 4, d0 = (jj & 15) * 4;
    size_t base = row + (isq ? 0 : DIM) + h * 128 + d0;
    float4 a1 = *(const float4*)&p[base];
    float4 b1 = *(const float4*)&p[base + sstride];
    float4 a2 = *(const float4*)&p[base + 64];
    float4 b2 = *(const float4*)&p[base + 64 + sstride];
    float4 x1, x2;
    x1.x = a1.x + b1.x; x1.y = a1.y + b1.y; x1.z = a1.z + b1.z; x1.w = a1.w + b1.w;
    x2.x = a2.x + b2.x; x2.y = a2.y + b2.y; x2.z = a2.z + b2.z; x2.w = a2.w + b2.w;
    float4 c = *(const float4*)&ct[r * HD + d0];
    float4 s = *(const float4*)&st[r * HD + d0];
    float sc = isq ? 0.08838834764831845f : 1.0f;
    ushort4v o1, o2;
    o1.x = f2bf((x1.x * c.x - x2.x * s.x) * sc);
    o1.y = f2bf((x1.y * c.y - x2.y * s.y) * sc);
    o1.z = f2bf((x1.z * c.z - x2.z * s.z) * sc);
    o1.w = f2bf((x1.w * c.w - x2.w * s.w) * sc);
    o2.x = f2bf((x2.x * c.x + x1.x * s.x) * sc);
    o2.y = f2bf((x2.y * c.y + x1.y * s.y) * sc);
    o2.z = f2bf((x2.z * c.z + x1.z * s.z) * sc);
    o2.w = f2bf((x2.w * c.w + x1.w * s.w) * sc);
    if (isq) {
      *(ushort4v*)&qb[(size_t)r * DIM + h * 128 + d0] = o1;
      *(ushort4v*)&qb[(size_t)r * DIM + h * 128 + d0 + 64] = o2;
    } else {
      *(ushort4v*)&kb[(size_t)r * 1024 + h * 128 + d0] = o1;
      *(ushort4v*)&kb[(size_t)r * 1024 + h * 128 + d0 + 64] = o2;
    }
  } else {
    int jj = j - 640;
    int c0 = jj * 4;
    size_t base = row + DIM + 1024 + c0;
    float4 a = *(const float4*)&p[base];
    float4 b = *(const float4*)&p[base + sstride];
    vtb[(size_t)(c0 + 0) * SEQ + r] = f2bf(a.x + b.x);
    vtb[(size_t)(c0 + 1) * SEQ + r] = f2bf(a.y + b.y);
    vtb[(size_t)(c0 + 2) * SEQ + r] = f2bf(a.z + b.z);
    vtb[(size_t)(c0 + 3) * SEQ + r] = f2bf(a.w + b.w);
  }
}

// ---------------- split-K reduce + residual -> f32 out ----------------
__global__ __launch_bounds__(256) void reduce4_res_kernel(const float* __restrict__ p,
                                                          const float* __restrict__ res,
                                                          float* __restrict__ out,
                                                          size_t sstride) {
  size_t i = ((size_t)blockIdx.x * 256 + threadIdx.x) * 4;
  float4 a = *(const float4*)&p[i];
  float4 b = *(const float4*)&p[i + sstride];
  float4 c = *(const float4*)&p[i + 2 * sstride];
  float4 d = *(const float4*)&p[i + 3 * sstride];
  float4 r = *(const float4*)&res[i];
  float4 o;
  o.x = a.x + b.x + c.x + d.x + r.x;
  o.y = a.y + b.y + c.y + d.y + r.y;
  o.z = a.z + b.z + c.z + d.z + r.z;
  o.w = a.w + b.w + c.w + d.w + r.w;
  *(float4*)&out[i] = o;
}

// ---------------- split-K reduce + residual + fused RMSNorm (one row/block) ----------------
__global__ __launch_bounds__(256) void reduce4_res_rms(const float* __restrict__ p,
                                                       const float* __restrict__ res,
                                                       const float* __restrict__ w,
                                                       float* __restrict__ xmed,
                                                       ushort* __restrict__ xn2,
                                                       size_t sstride) {
  int row = blockIdx.x, tid = threadIdx.x;
  size_t base = (size_t)row * DIM;
  float vals[16];
  float sq = 0.f;
#pragma unroll
  for (int c = 0; c < 4; c++) {
    size_t i = base + (tid + c * 256) * 4;
    float4 a = *(const float4*)&p[i];
    float4 b = *(const float4*)&p[i + sstride];
    float4 cc = *(const float4*)&p[i + 2 * sstride];
    float4 d = *(const float4*)&p[i + 3 * sstride];
    float4 r = *(const float4*)&res[i];
    float4 v;
    v.x = a.x + b.x + cc.x + d.x + r.x;
    v.y = a.y + b.y + cc.y + d.y + r.y;
    v.z = a.z + b.z + cc.z + d.z + r.z;
    v.w = a.w + b.w + cc.w + d.w + r.w;
    *(float4*)&xmed[i] = v;
    vals[c * 4 + 0] = v.x; vals[c * 4 + 1] = v.y;
    vals[c * 4 + 2] = v.z; vals[c * 4 + 3] = v.w;
    sq += v.x * v.x + v.y * v.y + v.z * v.z + v.w * v.w;
  }
#pragma unroll
  for (int off = 32; off >= 1; off >>= 1) sq += __shfl_down(sq, off);
  __shared__ float wsum[4];
  __shared__ float scale_s;
  int lane = tid & 63, wv = tid >> 6;
  if (lane == 0) wsum[wv] = sq;
  __syncthreads();
  if (tid == 0) {
    float t = wsum[0] + wsum[1] + wsum[2] + wsum[3];
    scale_s = rsqrtf(t / (float)DIM + 1e-5f);
  }
  __syncthreads();
  float scale = scale_s;
#pragma unroll
  for (int c = 0; c < 4; c++) {
    int off = (tid + c * 256) * 4;
    float4 wv4 = *(const float4*)&w[off];
    ushort4v ov;
    ov.x = f2bf(vals[c * 4 + 0] * scale * wv4.x);
    ov.y = f2bf(vals[c * 4 + 1] * scale * wv4.y);
    ov.z = f2bf(vals[c * 4 + 2] * scale * wv4.z);
    ov.w = f2bf(vals[c * 4 + 3] * scale * wv4.w);
    *(ushort4v*)&xn2[base + off] = ov;
  }
}

// ---------------- Flash attention (causal, GQA 4:1), kvh-XCD co-located, LPT order ----------------
__global__ __launch_bounds__(256) void attn_kernel(const ushort* __restrict__ q,
                                                   const ushort* __restrict__ k,
                                                   const ushort* __restrict__ vt,
                                                   ushort* __restrict__ o) {
  int flat = blockIdx.x + 16 * blockIdx.y;  // 0..511
  int kvh = flat & 7;
  int idx = flat >> 3;
  int h = kvh * 4 + (idx & 3);
  int qb = 15 - (idx >> 2);                 // descending work order
  int tid = threadIdx.x, lane = tid & 63, wave = tid >> 6;
  __shared__ ushort Ks[64][136];
  __shared__ ushort Vs[128][72];
  __shared__ ushort Ps[4][16][72];

  bf16x8 qf[4];
  int qrow = qb * 64 + wave * 16 + (lane & 15);
#pragma unroll
  for (int kk = 0; kk < 4; kk++)
    qf[kk] = *(const bf16x8*)&q[(size_t)qrow * DIM + h * HD + kk * 32 + (lane >> 4) * 8];

  f32x4 oacc[8] = {};
  float mrow[4], lrow[4];
  int qr[4];
#pragma unroll
  for (int j = 0; j < 4; j++) {
    mrow[j] = -INFINITY; lrow[j] = 0.f;
    qr[j] = qb * 64 + wave * 16 + (lane >> 4) * 4 + j;
  }

  for (int kt = 0; kt <= qb; kt++) {
    int key0 = kt * 64;
#pragma unroll
    for (int c = 0; c < 4; c++) {
      int e = tid * 32 + c * 8;
      int r = e >> 7, cc = e & 127;
      *(bf16x8*)&Ks[r][cc] =
          *(const bf16x8*)&k[(size_t)(key0 + r) * (NKVH * HD) + kvh * HD + cc];
      int r2 = e >> 6, cc2 = e & 63;
      *(bf16x8*)&Vs[r2][cc2] =
          *(const bf16x8*)&vt[(size_t)(kvh * HD + r2) * SEQ + key0 + cc2];
    }
    __syncthreads();

    f32x4 sf[4] = {};
#pragma unroll
    for (int fn = 0; fn < 4; fn++)
#pragma unroll
      for (int kk = 0; kk < 4; kk++) {
        bf16x8 kf = *(const bf16x8*)&Ks[fn * 16 + (lane & 15)][kk * 32 + (lane >> 4) * 8];
        sf[fn] = __builtin_amdgcn_mfma_f32_16x16x32_bf16(qf[kk], kf, sf[fn], 0, 0, 0);
      }

#pragma unroll
    for (int fn = 0; fn < 4; fn++) {
      int key = key0 + fn * 16 + (lane & 15);
#pragma unroll
      for (int j = 0; j < 4; j++)
        if (key > qr[j]) sf[fn][j] = -INFINITY;
    }

#pragma unroll
    for (int j = 0; j < 4; j++) {
      float mx = fmaxf(fmaxf(sf[0][j], sf[1][j]), fmaxf(sf[2][j], sf[3][j]));
#pragma unroll
      for (int off = 1; off < 16; off <<= 1) mx = fmaxf(mx, __shfl_xor(mx, off));
      float mnew = fmaxf(mrow[j], mx);
      float sc = __expf(mrow[j] - mnew);
      mrow[j] = mnew;
      float rs = 0.f;
#pragma unroll
      for (int fn = 0; fn < 4; fn++) {
        float p = __expf(sf[fn][j] - mnew);
        sf[fn][j] = p;
        rs += p;
      }
#pragma unroll
      for (int off = 1; off < 16; off <<= 1) rs += __shfl_xor(rs, off);
      lrow[j] = lrow[j] * sc + rs;
#pragma unroll
      for (int f2 = 0; f2 < 8; f2++) oacc[f2][j] *= sc;
    }

#pragma unroll
    for (int fn = 0; fn < 4; fn++)
#pragma unroll
      for (int j = 0; j < 4; j++)
        Ps[wave][(lane >> 4) * 4 + j][fn * 16 + (lane & 15)] = f2bf(sf[fn][j]);

#pragma unroll
    for (int kk = 0; kk < 2; kk++) {
      bf16x8 pf = *(const bf16x8*)&Ps[wave][lane & 15][kk * 32 + (lane >> 4) * 8];
#pragma unroll
      for (int f2 = 0; f2 < 8; f2++) {
        bf16x8 vf = *(const bf16x8*)&Vs[f2 * 16 + (lane & 15)][kk * 32 + (lane >> 4) * 8];
        oacc[f2] = __builtin_amdgcn_mfma_f32_16x16x32_bf16(pf, vf, oacc[f2], 0, 0, 0);
      }
    }
    __syncthreads();
  }

#pragma unroll
  for (int j = 0; j < 4; j++) {
    float inv = 1.f / lrow[j];
#pragma unroll
    for (int f2 = 0; f2 < 8; f2++)
      o[(size_t)qr[j] * DIM + h * HD + f2 * 16 + (lane & 15)] = f2bf(oacc[f2][j] * inv);
  }
}

extern "C" void kernel_launch(void* const* d_in, const int* in_sizes, int n_in,
                              void* d_out, int out_size, void* d_ws, size_t ws_size,
                              hipStream_t stream) {
  const float* x    = (const float*)d_in[0];
  const float* w1   = (const float*)d_in[1];
  const float* w2   = (const float*)d_in[2];
  const float* cosT = (const float*)d_in[3];
  const float* sinT = (const float*)d_in[4];
  const float* wq = (const float*)d_in[6];
  const float* la_q = (const float*)d_in[7];
  const float* lb_q = (const float*)d_in[8];
  const float* wk = (const float*)d_in[9];
  const float* la_k = (const float*)d_in[10];
  const float* lb_k = (const float*)d_in[11];
  const float* wv = (const float*)d_in[12];
  const float* la_v = (const float*)d_in[13];
  const float* lb_v = (const float*)d_in[14];
  const float* wo = (const float*)d_in[15];
  const float* la_o = (const float*)d_in[16];
  const float* lb_o = (const float*)d_in[17];
  const float* wg = (const float*)d_in[18];
  const float* la_g = (const float*)d_in[19];
  const float* lb_g = (const float*)d_in[20];
  const float* wu = (const float*)d_in[21];
  const float* la_u = (const float*)d_in[22];
  const float* lb_u = (const float*)d_in[23];
  const float* wd = (const float*)d_in[24];
  const float* la_d = (const float*)d_in[25];
  const float* lb_d = (const float*)d_in[26];
  float* out = (float*)d_out;

  char* ws = (char*)d_ws;
  ushort* xn1 = (ushort*)ws;  ws += (size_t)SEQ * DIM * 2;
  ushort* qb  = (ushort*)ws;  ws += (size_t)SEQ * DIM * 2;
  ushort* kb  = (ushort*)ws;  ws += (size_t)SEQ * NKVH * HD * 2;
  ushort* vtb = (ushort*)ws;  ws += (size_t)SEQ * NKVH * HD * 2;
  ushort* ob  = (ushort*)ws;  ws += (size_t)SEQ * DIM * 2;
  float*  xmed= (float*)ws;   ws += (size_t)SEQ * DIM * 4;
  ushort* xn2 = (ushort*)ws;  ws += (size_t)SEQ * DIM * 2;
  ushort* gate= (ushort*)ws;  ws += (size_t)SEQ * FF * 2;
  ushort* up  = (ushort*)ws;  ws += (size_t)SEQ * FF * 2;
  ushort* hb  = (ushort*)ws;  ws += (size_t)SEQ * FF * 2;
  ushort* t_q = (ushort*)ws; ws += SEQ * LR * 2;
  ushort* t_k = (ushort*)ws; ws += SEQ * LR * 2;
  ushort* t_v = (ushort*)ws; ws += SEQ * LR * 2;
  ushort* t_o = (ushort*)ws; ws += SEQ * LR * 2;
  ushort* t_g = (ushort*)ws; ws += SEQ * LR * 2;
  ushort* t_u = (ushort*)ws; ws += SEQ * LR * 2;
  ushort* t_d = (ushort*)ws; ws += SEQ * LR * 2;

  float* pbuf1 = (float*)gate;  // QKV / wo partials: gate..hb dead then
  float* pbuf2 = (float*)xn2;   // wd partials: xn2+gate+up dead then

  size_t snd = (size_t)SEQ * DIM;

  // 1) norm + fused lora-A (q,k,v share xn1)
  rmsnorm_kernel<<<SEQ, 256, 0, stream>>>(x, w1, xn1);
  lora_a_kernel<3><<<SEQ, 256, 0, stream>>>(xn1, la_q, la_k, la_v, t_q, t_k, t_v, DIM);

  // 2) fused QKV GEMM (split-K2, fused dequant) -> reduce + fused RoPE + V-transpose
  gemm256_kernel<3><<<dim3((DIM + 2048) / 256, SEQ / 256, 2), 512, 0, stream>>>(
      xn1, wq, wk, wv, lb_q, lb_k, lb_v, t_q, t_k, t_v,
      nullptr, nullptr, nullptr, DIM, DIM + 1024,
      pbuf1, SEQ, DIM + 2048, DIM, 32);
  reduce2_qkv_rope<<<SEQ * 896 / 256, 256, 0, stream>>>(pbuf1, cosT, sinT, qb, kb, vtb);

  // 3) attention
  attn_kernel<<<dim3(SEQ / 64, NH), 256, 0, stream>>>(qb, kb, vtb, ob);

  // 4) WO (split-K4, fused dequant) + residual + fused RMSNorm -> xmed, xn2
  lora_a_kernel<1><<<SEQ, 256, 0, stream>>>(ob, la_o, la_o, la_o, t_o, t_o, t_o, DIM);
  gemm256_kernel<3><<<dim3(DIM / 256, SEQ / 256, 4), 512, 0, stream>>>(
      ob, wo, wo, wo, lb_o, lb_o, lb_o, t_o, t_o, t_o,
      nullptr, nullptr, nullptr, DIM, DIM,
      pbuf1, SEQ, DIM, DIM, 16);
  reduce4_res_rms<<<SEQ, 256, 0, stream>>>(pbuf1, x, w2, xmed, xn2, snd);

  // 5) FFN: COMBINED gate+up GEMM (N=2*FF, 448 blocks), then silu-mul
  lora_a_kernel<2><<<SEQ, 256, 0, stream>>>(xn2, la_g, la_u, la_u, t_g, t_u, t_u, DIM);
  gemm256_kernel<0><<<dim3(2 * FF / 256, SEQ / 256, 1), 512, 0, stream>>>(
      xn2, wg, wu, wu, lb_g, lb_u, lb_u, t_g, t_u, t_u,
      gate, up, up, FF, 2 * FF,
      nullptr, SEQ, 2 * FF, DIM, DIM / 64);
  silu_mul_kernel<<<SEQ * FF / 8 / 256, 256, 0, stream>>>(gate, up, hb);
  lora_a_kernel<1><<<SEQ, 256, 0, stream>>>(hb, la_d, la_d, la_d, t_d, t_d, t_d, FF);
  gemm256_kernel<3><<<dim3(DIM / 256, SEQ / 256, 4), 512, 0, stream>>>(
      hb, wd, wd, wd, lb_d, lb_d, lb_d, t_d, t_d, t_d,
      nullptr, nullptr, nullptr, DIM, DIM,
      pbuf2, SEQ, DIM, FF, FF / 4 / 64);
  reduce4_res_kernel<<<snd / 1024, 256, 0, stream>>>(pbuf2, xmed, out, snd);
}

// Round 19
// 863.501 us; speedup vs baseline: 5.7163x; 1.0114x over previous
//
#include <hip/hip_runtime.h>
#include <hip/hip_bf16.h>
#include <math.h>

#define SEQ 1024
#define DIM 4096
#define NH 32
#define HD 128
#define NKVH 8
#define FF 14336
#define LR 16

typedef __attribute__((ext_vector_type(8))) short bf16x8;
typedef __attribute__((ext_vector_type(4))) float f32x4;
typedef __attribute__((ext_vector_type(4))) ushort ushort4v;
typedef __attribute__((ext_vector_type(4))) unsigned int u32x4;

__device__ __forceinline__ ushort f2bf(float f) {
  union { float f; unsigned u; } v; v.f = f;
  unsigned r = (v.u + 0x7FFFu + ((v.u >> 16) & 1u)) >> 16;
  return (ushort)r;
}
__device__ __forceinline__ float bf2f(ushort h) {
  union { unsigned u; float f; } v; v.u = ((unsigned)h) << 16;
  return v.f;
}
__device__ __forceinline__ unsigned cvtpk(float a, float b) {
  unsigned r;
  asm("v_cvt_pk_bf16_f32 %0, %1, %2" : "=v"(r) : "v"(a), "v"(b));
  return r;
}
// sum of 4 bf16 partial slices, vectorized 4-wide
__device__ __forceinline__ float4 sum4v(const ushort* __restrict__ p, size_t idx, size_t ss) {
  float4 r = {0.f, 0.f, 0.f, 0.f};
#pragma unroll
  for (int s = 0; s < 4; s++) {
    ushort4v v = *(const ushort4v*)&p[idx + (size_t)s * ss];
    r.x += bf2f(v.x); r.y += bf2f(v.y); r.z += bf2f(v.z); r.w += bf2f(v.w);
  }
  return r;
}

__device__ __forceinline__ void gload_lds16(const void* g, void* l) {
  __builtin_amdgcn_global_load_lds(
      (const __attribute__((address_space(1))) void*)g,
      (__attribute__((address_space(3))) void*)l, 16, 0, 0);
}

// ---------------- RMSNorm: f32 in -> bf16 out ----------------
__global__ __launch_bounds__(256) void rmsnorm_kernel(const float* __restrict__ x,
                                                      const float* __restrict__ w,
                                                      ushort* __restrict__ out) {
  int row = blockIdx.x;
  int tid = threadIdx.x;
  const float* xr = x + (size_t)row * DIM;
  float vals[16];
  float s = 0.f;
#pragma unroll
  for (int c = 0; c < 4; c++) {
    float4 v = *(const float4*)&xr[(tid + c * 256) * 4];
    vals[c * 4 + 0] = v.x; vals[c * 4 + 1] = v.y;
    vals[c * 4 + 2] = v.z; vals[c * 4 + 3] = v.w;
    s += v.x * v.x + v.y * v.y + v.z * v.z + v.w * v.w;
  }
#pragma unroll
  for (int off = 32; off >= 1; off >>= 1) s += __shfl_down(s, off);
  __shared__ float wsum[4];
  __shared__ float scale_s;
  int lane = tid & 63, wv = tid >> 6;
  if (lane == 0) wsum[wv] = s;
  __syncthreads();
  if (tid == 0) {
    float t = wsum[0] + wsum[1] + wsum[2] + wsum[3];
    scale_s = rsqrtf(t / (float)DIM + 1e-5f);
  }
  __syncthreads();
  float scale = scale_s;
  ushort* orow = out + (size_t)row * DIM;
#pragma unroll
  for (int c = 0; c < 4; c++) {
    int base = (tid + c * 256) * 4;
    float4 wv4 = *(const float4*)&w[base];
    ushort4v ov;
    ov.x = f2bf(vals[c * 4 + 0] * scale * wv4.x);
    ov.y = f2bf(vals[c * 4 + 1] * scale * wv4.y);
    ov.z = f2bf(vals[c * 4 + 2] * scale * wv4.z);
    ov.w = f2bf(vals[c * 4 + 3] * scale * wv4.w);
    *(ushort4v*)&orow[base] = ov;
  }
}

// ---------------- LoRA A: t_l[m][16] = A[m] @ la_l, one row per block ----------------
template <int NL>
__global__ __launch_bounds__(256) void lora_a_kernel(
    const ushort* __restrict__ A,
    const float* __restrict__ la0, const float* __restrict__ la1,
    const float* __restrict__ la2,
    ushort* __restrict__ t0, ushort* __restrict__ t1, ushort* __restrict__ t2,
    int K) {
  int m = blockIdx.x, i = threadIdx.x;
  float acc[NL][16];
#pragma unroll
  for (int l = 0; l < NL; l++)
#pragma unroll
    for (int n = 0; n < 16; n++) acc[l][n] = 0.f;

  const ushort* Arow = A + (size_t)m * K;
  int nc = K >> 8;
  for (int c = 0; c < nc; c++) {
    int k = c * 256 + i;
    float a = bf2f(Arow[k]);
#pragma unroll
    for (int l = 0; l < NL; l++) {
      const float* lap = (l == 0 ? la0 : (l == 1 ? la1 : la2)) + (size_t)k * 16;
#pragma unroll
      for (int q = 0; q < 4; q++) {
        float4 lv = *(const float4*)&lap[q * 4];
        acc[l][q * 4 + 0] += a * lv.x;
        acc[l][q * 4 + 1] += a * lv.y;
        acc[l][q * 4 + 2] += a * lv.z;
        acc[l][q * 4 + 3] += a * lv.w;
      }
    }
  }

  __shared__ float red[256][17];
  __shared__ float red2[16][17];
#pragma unroll
  for (int l = 0; l < NL; l++) {
    __syncthreads();
#pragma unroll
    for (int n = 0; n < 16; n++) red[i][n] = acc[l][n];
    __syncthreads();
    {
      int g = i >> 4, n = i & 15;
      float s = 0.f;
#pragma unroll
      for (int j = 0; j < 16; j++) s += red[g * 16 + j][n];
      red2[g][n] = s;
    }
    __syncthreads();
    if (i < 16) {
      float s2 = 0.f;
#pragma unroll
      for (int g2 = 0; g2 < 16; g2++) s2 += red2[g2][i];
      ushort* tp = (l == 0 ? t0 : (l == 1 ? t1 : t2));
      tp[(size_t)m * LR + i] = f2bf(s2);
    }
  }
}

// ================= 256x256 GEMM, 8 waves, 8-phase dbuf, fused dequant (r15 proven core) =========
// 3-segment weight/lora/output select. WM0: bf16 out (row stride wseg); WM3: BF16 split-K
// partial slice [z][M][N]. cvt_pk dequant; panel co-location; XOR swizzle.
template <int WM>
__global__ __launch_bounds__(512) void gemm256_kernel(
    const ushort* __restrict__ A,
    const float* __restrict__ W0, const float* __restrict__ W1, const float* __restrict__ W2,
    const float* __restrict__ lb0, const float* __restrict__ lb1, const float* __restrict__ lb2,
    const ushort* __restrict__ t0, const ushort* __restrict__ t1, const ushort* __restrict__ t2,
    void* __restrict__ o0, void* __restrict__ o1, void* __restrict__ o2,
    int c1, int c2, void* __restrict__ outp, int M, int N, int K, int nkp) {
  __shared__ __align__(16) ushort As[2][256 * 64];
  __shared__ __align__(16) ushort Bs[2][256 * 64];
  int tid = threadIdx.x;
  int lane = tid & 63, wave = tid >> 6;
  int wm = wave >> 2, wn = wave & 3;

  // ---- T1 XCD swizzle + panel-sharer-adjacent decode ----
  int gx = gridDim.x, gy = gridDim.y, gz = gridDim.z;
  int flat = blockIdx.x + gx * (blockIdx.y + gy * blockIdx.z);
  int nwg = gx * gy * gz;
  int q = nwg >> 3, r = nwg & 7;
  int xcd = flat & 7;
  int wgid = (xcd < r ? xcd * (q + 1) : r * (q + 1) + (xcd - r) * q) + (flat >> 3);
  int sh = gy * gz;
  int bx = wgid / sh;
  int rem = wgid - bx * sh;
  int z = rem / gy;
  int by = rem - z * gy;

  int n0 = bx * 256, m0 = by * 256;
  int k0 = z * nkp;

  // segment select (weight + lora + out)
  const float* Wp; const float* lbp; const ushort* tp; void* osel; int nseg, wseg;
  if (n0 < c1)      { Wp = W0; lbp = lb0; tp = t0; osel = o0; nseg = n0;      wseg = c1; }
  else if (n0 < c2) { Wp = W1; lbp = lb1; tp = t1; osel = o1; nseg = n0 - c1; wseg = c2 - c1; }
  else              { Wp = W2; lbp = lb2; tp = t2; osel = o2; nseg = n0 - c2; wseg = N - c2; }

  // A staging
  int srow = tid >> 3;
  int sswz = ((tid & 7) ^ (srow & 7)) * 8;
  const ushort* Ab = A + (size_t)(m0 + srow) * K + sswz;
  // B reg-staging source (linear; swizzle at ds_write)
  const float* Wbase = Wp + (size_t)(nseg + srow) * K + (tid & 7) * 8;

  f32x4 acc[8][4] = {};
  float4 breg[8];

#define SHALF(kt, b, h)                                                       \
  _Pragma("unroll") for (int i = 2 * (h); i < 2 * (h) + 2; i++) {             \
    gload_lds16(Ab + (size_t)(i * 64) * K + (size_t)(kt) * 64,                \
                &As[b][wave * 512 + i * 4096]);                               \
  }
#define BLOAD(kt, h)                                                          \
  {                                                                           \
    const float* gp = Wbase + (size_t)((h) * 128) * K + (size_t)(kt) * 64;    \
    breg[(h) * 4 + 0] = *(const float4*)gp;                                   \
    breg[(h) * 4 + 1] = *(const float4*)(gp + 4);                             \
    breg[(h) * 4 + 2] = *(const float4*)(gp + (size_t)64 * K);                \
    breg[(h) * 4 + 3] = *(const float4*)(gp + (size_t)64 * K + 4);            \
  }
#define WRITE_B(b)                                                            \
  _Pragma("unroll") for (int h = 0; h < 2; h++)                               \
  _Pragma("unroll") for (int j = 0; j < 2; j++) {                             \
    int rr = h * 128 + j * 64 + srow;                                         \
    float4 lo = breg[h * 4 + j * 2 + 0];                                      \
    float4 hi = breg[h * 4 + j * 2 + 1];                                      \
    u32x4 v;                                                                  \
    v.x = cvtpk(lo.x, lo.y); v.y = cvtpk(lo.z, lo.w);                         \
    v.z = cvtpk(hi.x, hi.y); v.w = cvtpk(hi.z, hi.w);                         \
    *(u32x4*)&Bs[b][rr * 64 + (((tid & 7) ^ (rr & 7))) * 8] = v;              \
  }
#define LDFRAG(buf, rr, ks) \
  (*(const bf16x8*)&(buf)[(rr) * 64 + (((ks) * 4 + (lane >> 4)) ^ ((rr) & 7)) * 8])

  // ---- prologue ----
  BLOAD(k0, 0); BLOAD(k0, 1);
  SHALF(k0, 0, 0); SHALF(k0, 0, 1);
  asm volatile("s_waitcnt vmcnt(4)" ::: "memory");
  WRITE_B(0);
  if (nkp > 1) { BLOAD(k0 + 1, 0); BLOAD(k0 + 1, 1); }
  if (nkp > 1) asm volatile("s_waitcnt vmcnt(8)" ::: "memory");
  else         asm volatile("s_waitcnt vmcnt(0)" ::: "memory");
  asm volatile("s_waitcnt lgkmcnt(0)" ::: "memory");
  __builtin_amdgcn_s_barrier();
  __builtin_amdgcn_sched_barrier(0);

  for (int tau = 0; tau < nkp; tau++) {
    int b = tau & 1;
    bool s1 = (tau + 1 < nkp), s2 = (tau + 2 < nkp);
    const ushort* as = As[b];
    const ushort* bs = Bs[b];
    bf16x8 bfr[4][2];
#pragma unroll
    for (int p = 0; p < 4; p++) {
      bf16x8 af[2][2];
#pragma unroll
      for (int qq = 0; qq < 2; qq++) {
        int ra = wm * 128 + (p * 2 + qq) * 16 + (lane & 15);
#pragma unroll
        for (int ks = 0; ks < 2; ks++) af[qq][ks] = LDFRAG(as, ra, ks);
      }
      if (p == 0) {
#pragma unroll
        for (int f = 0; f < 4; f++) {
          int rb = wn * 64 + f * 16 + (lane & 15);
#pragma unroll
          for (int ks = 0; ks < 2; ks++) bfr[f][ks] = LDFRAG(bs, rb, ks);
        }
      }
      if (p == 0 && s1) { SHALF(k0 + tau + 1, b ^ 1, 0); }
      if (p == 1 && s1) { SHALF(k0 + tau + 1, b ^ 1, 1); }
      if (p == 2 && s2) { BLOAD(k0 + tau + 2, 0); }
      if (p == 3 && s2) { BLOAD(k0 + tau + 2, 1); }
      __builtin_amdgcn_sched_barrier(0);
      __builtin_amdgcn_s_barrier();
      asm volatile("s_waitcnt lgkmcnt(0)" ::: "memory");
      __builtin_amdgcn_sched_barrier(0);
      __builtin_amdgcn_s_setprio(1);
#pragma unroll
      for (int qq = 0; qq < 2; qq++)
#pragma unroll
        for (int fn = 0; fn < 4; fn++)
#pragma unroll
          for (int ks = 0; ks < 2; ks++)
            acc[p * 2 + qq][fn] = __builtin_amdgcn_mfma_f32_16x16x32_bf16(
                af[qq][ks], bfr[fn][ks], acc[p * 2 + qq][fn], 0, 0, 0);
      __builtin_amdgcn_s_setprio(0);
      __builtin_amdgcn_sched_barrier(0);
      if (p == 1 && s1) {
        asm volatile("s_waitcnt vmcnt(4)" ::: "memory");
        WRITE_B(b ^ 1);
        __builtin_amdgcn_sched_barrier(0);
      }
      if (p == 3) {
        if (s2) asm volatile("s_waitcnt vmcnt(8)" ::: "memory");
        else    asm volatile("s_waitcnt vmcnt(0)" ::: "memory");
      }
      __builtin_amdgcn_s_barrier();
      __builtin_amdgcn_sched_barrier(0);
    }
  }
#undef SHALF
#undef BLOAD
#undef WRITE_B

  // ---- LoRA K-extension (split 0 only) ----
  if (z == 0) {
#pragma unroll
    for (int it = 0; it < 2; it++) {
      int task = tid + it * 512;
      int rr = task >> 2, ls = task & 3;
      int ph = ls ^ (rr & 7);
      bf16x8 avv = {};
      bf16x8 bvv = {};
      if (ls < 2) {
        avv = *(const bf16x8*)&tp[(size_t)(m0 + rr) * LR + ls * 8];
#pragma unroll
        for (int j = 0; j < 8; j++)
          bvv[j] = (short)f2bf(lbp[(size_t)(ls * 8 + j) * wseg + nseg + rr]);
      }
      *(bf16x8*)&As[0][rr * 64 + ph * 8] = avv;
      *(bf16x8*)&Bs[0][rr * 64 + ph * 8] = bvv;
    }
    __syncthreads();
    bf16x8 af[8], bfr[4];
#pragma unroll
    for (int f = 0; f < 8; f++) {
      int ra = wm * 128 + f * 16 + (lane & 15);
      af[f] = LDFRAG(As[0], ra, 0);
    }
#pragma unroll
    for (int f = 0; f < 4; f++) {
      int rb = wn * 64 + f * 16 + (lane & 15);
      bfr[f] = LDFRAG(Bs[0], rb, 0);
    }
#pragma unroll
    for (int fm = 0; fm < 8; fm++)
#pragma unroll
      for (int fn = 0; fn < 4; fn++)
        acc[fm][fn] = __builtin_amdgcn_mfma_f32_16x16x32_bf16(af[fm], bfr[fn], acc[fm][fn], 0, 0, 0);
  }
#undef LDFRAG

  // ---- write ----
#pragma unroll
  for (int fm = 0; fm < 8; fm++) {
#pragma unroll
    for (int j = 0; j < 4; j++) {
      int mg = m0 + wm * 128 + fm * 16 + (lane >> 4) * 4 + j;
#pragma unroll
      for (int fn = 0; fn < 4; fn++) {
        int ncol = wn * 64 + fn * 16 + (lane & 15);  // col within 256-tile
        float v = acc[fm][fn][j];
        if (WM == 0) {
          ((ushort*)osel)[(size_t)mg * wseg + nseg + ncol] = f2bf(v);
        } else {
          // bf16 split-K partial slice
          ((ushort*)outp)[((size_t)z * M + mg) * (size_t)N + n0 + ncol] = f2bf(v);
        }
      }
    }
  }
}

// ---------------- h = silu(gate) * up ----------------
__global__ __launch_bounds__(256) void silu_mul_kernel(const ushort* __restrict__ g,
                                                       const ushort* __restrict__ u,
                                                       ushort* __restrict__ h) {
  size_t idx = (size_t)(blockIdx.x * 256 + threadIdx.x) * 8;
  bf16x8 gv = *(const bf16x8*)&g[idx];
  bf16x8 uv = *(const bf16x8*)&u[idx];
  bf16x8 hv;
#pragma unroll
  for (int i = 0; i < 8; i++) {
    float gf = bf2f((ushort)gv[i]);
    float uf = bf2f((ushort)uv[i]);
    float sv = gf / (1.f + __expf(-gf));
    hv[i] = (short)f2bf(sv * uf);
  }
  *(bf16x8*)&h[idx] = hv;
}

// ---------------- QKV reduce (4 bf16 slices) + fused RoPE + V transpose ----------------
__global__ __launch_bounds__(256) void reduce4_qkv_rope(const ushort* __restrict__ p,
                                                        const float* __restrict__ ct,
                                                        const float* __restrict__ st,
                                                        ushort* __restrict__ qb,
                                                        ushort* __restrict__ kb,
                                                        ushort* __restrict__ vtb) {
  int gidx = blockIdx.x * 256 + threadIdx.x;
  int r = gidx / 896, j = gidx - r * 896;
  size_t row = (size_t)r * 6144;
  size_t ss = (size_t)SEQ * 6144;
  if (j < 640) {
    bool isq = j < 512;
    int jj = isq ? j : j - 512;
    int h = jj >> 4, d0 = (jj & 15) * 4;
    size_t base = row + (isq ? 0 : DIM) + h * 128 + d0;
    float4 x1 = sum4v(p, base, ss);
    float4 x2 = sum4v(p, base + 64, ss);
    float4 c = *(const float4*)&ct[r * HD + d0];
    float4 s = *(const float4*)&st[r * HD + d0];
    float sc = isq ? 0.08838834764831845f : 1.0f;
    ushort4v o1, o2;
    o1.x = f2bf((x1.x * c.x - x2.x * s.x) * sc);
    o1.y = f2bf((x1.y * c.y - x2.y * s.y) * sc);
    o1.z = f2bf((x1.z * c.z - x2.z * s.z) * sc);
    o1.w = f2bf((x1.w * c.w - x2.w * s.w) * sc);
    o2.x = f2bf((x2.x * c.x + x1.x * s.x) * sc);
    o2.y = f2bf((x2.y * c.y + x1.y * s.y) * sc);
    o2.z = f2bf((x2.z * c.z + x1.z * s.z) * sc);
    o2.w = f2bf((x2.w * c.w + x1.w * s.w) * sc);
    if (isq) {
      *(ushort4v*)&qb[(size_t)r * DIM + h * 128 + d0] = o1;
      *(ushort4v*)&qb[(size_t)r * DIM + h * 128 + d0 + 64] = o2;
    } else {
      *(ushort4v*)&kb[(size_t)r * 1024 + h * 128 + d0] = o1;
      *(ushort4v*)&kb[(size_t)r * 1024 + h * 128 + d0 + 64] = o2;
    }
  } else {
    int jj = j - 640;
    int c0 = jj * 4;
    size_t base = row + DIM + 1024 + c0;
    float4 sv = sum4v(p, base, ss);
    vtb[(size_t)(c0 + 0) * SEQ + r] = f2bf(sv.x);
    vtb[(size_t)(c0 + 1) * SEQ + r] = f2bf(sv.y);
    vtb[(size_t)(c0 + 2) * SEQ + r] = f2bf(sv.z);
    vtb[(size_t)(c0 + 3) * SEQ + r] = f2bf(sv.w);
  }
}

// ---------------- split-K reduce (4 bf16 slices) + residual -> f32 out ----------------
__global__ __launch_bounds__(256) void reduce4_res_kernel(const ushort* __restrict__ p,
                                                          const float* __restrict__ res,
                                                          float* __restrict__ out,
                                                          size_t sstride) {
  size_t i = ((size_t)blockIdx.x * 256 + threadIdx.x) * 4;
  float4 sv = sum4v(p, i, sstride);
  float4 r = *(const float4*)&res[i];
  float4 o;
  o.x = sv.x + r.x; o.y = sv.y + r.y; o.z = sv.z + r.z; o.w = sv.w + r.w;
  *(float4*)&out[i] = o;
}

// ---------------- split-K reduce + residual + fused RMSNorm (one row/block) ----------------
__global__ __launch_bounds__(256) void reduce4_res_rms(const ushort* __restrict__ p,
                                                       const float* __restrict__ res,
                                                       const float* __restrict__ w,
                                                       float* __restrict__ xmed,
                                                       ushort* __restrict__ xn2,
                                                       size_t sstride) {
  int row = blockIdx.x, tid = threadIdx.x;
  size_t base = (size_t)row * DIM;
  float vals[16];
  float sq = 0.f;
#pragma unroll
  for (int c = 0; c < 4; c++) {
    size_t i = base + (tid + c * 256) * 4;
    float4 sv = sum4v(p, i, sstride);
    float4 r = *(const float4*)&res[i];
    float4 v;
    v.x = sv.x + r.x; v.y = sv.y + r.y; v.z = sv.z + r.z; v.w = sv.w + r.w;
    *(float4*)&xmed[i] = v;
    vals[c * 4 + 0] = v.x; vals[c * 4 + 1] = v.y;
    vals[c * 4 + 2] = v.z; vals[c * 4 + 3] = v.w;
    sq += v.x * v.x + v.y * v.y + v.z * v.z + v.w * v.w;
  }
#pragma unroll
  for (int off = 32; off >= 1; off >>= 1) sq += __shfl_down(sq, off);
  __shared__ float wsum[4];
  __shared__ float scale_s;
  int lane = tid & 63, wv = tid >> 6;
  if (lane == 0) wsum[wv] = sq;
  __syncthreads();
  if (tid == 0) {
    float t = wsum[0] + wsum[1] + wsum[2] + wsum[3];
    scale_s = rsqrtf(t / (float)DIM + 1e-5f);
  }
  __syncthreads();
  float scale = scale_s;
#pragma unroll
  for (int c = 0; c < 4; c++) {
    int off = (tid + c * 256) * 4;
    float4 wv4 = *(const float4*)&w[off];
    ushort4v ov;
    ov.x = f2bf(vals[c * 4 + 0] * scale * wv4.x);
    ov.y = f2bf(vals[c * 4 + 1] * scale * wv4.y);
    ov.z = f2bf(vals[c * 4 + 2] * scale * wv4.z);
    ov.w = f2bf(vals[c * 4 + 3] * scale * wv4.w);
    *(ushort4v*)&xn2[base + off] = ov;
  }
}

// ---------------- Flash attention (causal, GQA 4:1), kvh-XCD co-located, LPT order ----------------
__global__ __launch_bounds__(256) void attn_kernel(const ushort* __restrict__ q,
                                                   const ushort* __restrict__ k,
                                                   const ushort* __restrict__ vt,
                                                   ushort* __restrict__ o) {
  int flat = blockIdx.x + 16 * blockIdx.y;  // 0..511
  int kvh = flat & 7;
  int idx = flat >> 3;
  int h = kvh * 4 + (idx & 3);
  int qb = 15 - (idx >> 2);                 // descending work order
  int tid = threadIdx.x, lane = tid & 63, wave = tid >> 6;
  __shared__ ushort Ks[64][136];
  __shared__ ushort Vs[128][72];
  __shared__ ushort Ps[4][16][72];

  bf16x8 qf[4];
  int qrow = qb * 64 + wave * 16 + (lane & 15);
#pragma unroll
  for (int kk = 0; kk < 4; kk++)
    qf[kk] = *(const bf16x8*)&q[(size_t)qrow * DIM + h * HD + kk * 32 + (lane >> 4) * 8];

  f32x4 oacc[8] = {};
  float mrow[4], lrow[4];
  int qr[4];
#pragma unroll
  for (int j = 0; j < 4; j++) {
    mrow[j] = -INFINITY; lrow[j] = 0.f;
    qr[j] = qb * 64 + wave * 16 + (lane >> 4) * 4 + j;
  }

  for (int kt = 0; kt <= qb; kt++) {
    int key0 = kt * 64;
#pragma unroll
    for (int c = 0; c < 4; c++) {
      int e = tid * 32 + c * 8;
      int r = e >> 7, cc = e & 127;
      *(bf16x8*)&Ks[r][cc] =
          *(const bf16x8*)&k[(size_t)(key0 + r) * (NKVH * HD) + kvh * HD + cc];
      int r2 = e >> 6, cc2 = e & 63;
      *(bf16x8*)&Vs[r2][cc2] =
          *(const bf16x8*)&vt[(size_t)(kvh * HD + r2) * SEQ + key0 + cc2];
    }
    __syncthreads();

    f32x4 sf[4] = {};
#pragma unroll
    for (int fn = 0; fn < 4; fn++)
#pragma unroll
      for (int kk = 0; kk < 4; kk++) {
        bf16x8 kf = *(const bf16x8*)&Ks[fn * 16 + (lane & 15)][kk * 32 + (lane >> 4) * 8];
        sf[fn] = __builtin_amdgcn_mfma_f32_16x16x32_bf16(qf[kk], kf, sf[fn], 0, 0, 0);
      }

#pragma unroll
    for (int fn = 0; fn < 4; fn++) {
      int key = key0 + fn * 16 + (lane & 15);
#pragma unroll
      for (int j = 0; j < 4; j++)
        if (key > qr[j]) sf[fn][j] = -INFINITY;
    }

#pragma unroll
    for (int j = 0; j < 4; j++) {
      float mx = fmaxf(fmaxf(sf[0][j], sf[1][j]), fmaxf(sf[2][j], sf[3][j]));
#pragma unroll
      for (int off = 1; off < 16; off <<= 1) mx = fmaxf(mx, __shfl_xor(mx, off));
      float mnew = fmaxf(mrow[j], mx);
      float sc = __expf(mrow[j] - mnew);
      mrow[j] = mnew;
      float rs = 0.f;
#pragma unroll
      for (int fn = 0; fn < 4; fn++) {
        float p = __expf(sf[fn][j] - mnew);
        sf[fn][j] = p;
        rs += p;
      }
#pragma unroll
      for (int off = 1; off < 16; off <<= 1) rs += __shfl_xor(rs, off);
      lrow[j] = lrow[j] * sc + rs;
#pragma unroll
      for (int f2 = 0; f2 < 8; f2++) oacc[f2][j] *= sc;
    }

#pragma unroll
    for (int fn = 0; fn < 4; fn++)
#pragma unroll
      for (int j = 0; j < 4; j++)
        Ps[wave][(lane >> 4) * 4 + j][fn * 16 + (lane & 15)] = f2bf(sf[fn][j]);

#pragma unroll
    for (int kk = 0; kk < 2; kk++) {
      bf16x8 pf = *(const bf16x8*)&Ps[wave][lane & 15][kk * 32 + (lane >> 4) * 8];
#pragma unroll
      for (int f2 = 0; f2 < 8; f2++) {
        bf16x8 vf = *(const bf16x8*)&Vs[f2 * 16 + (lane & 15)][kk * 32 + (lane >> 4) * 8];
        oacc[f2] = __builtin_amdgcn_mfma_f32_16x16x32_bf16(pf, vf, oacc[f2], 0, 0, 0);
      }
    }
    __syncthreads();
  }

#pragma unroll
  for (int j = 0; j < 4; j++) {
    float inv = 1.f / lrow[j];
#pragma unroll
    for (int f2 = 0; f2 < 8; f2++)
      o[(size_t)qr[j] * DIM + h * HD + f2 * 16 + (lane & 15)] = f2bf(oacc[f2][j] * inv);
  }
}

extern "C" void kernel_launch(void* const* d_in, const int* in_sizes, int n_in,
                              void* d_out, int out_size, void* d_ws, size_t ws_size,
                              hipStream_t stream) {
  const float* x    = (const float*)d_in[0];
  const float* w1   = (const float*)d_in[1];
  const float* w2   = (const float*)d_in[2];
  const float* cosT = (const float*)d_in[3];
  const float* sinT = (const float*)d_in[4];
  const float* wq = (const float*)d_in[6];
  const float* la_q = (const float*)d_in[7];
  const float* lb_q = (const float*)d_in[8];
  const float* wk = (const float*)d_in[9];
  const float* la_k = (const float*)d_in[10];
  const float* lb_k = (const float*)d_in[11];
  const float* wv = (const float*)d_in[12];
  const float* la_v = (const float*)d_in[13];
  const float* lb_v = (const float*)d_in[14];
  const float* wo = (const float*)d_in[15];
  const float* la_o = (const float*)d_in[16];
  const float* lb_o = (const float*)d_in[17];
  const float* wg = (const float*)d_in[18];
  const float* la_g = (const float*)d_in[19];
  const float* lb_g = (const float*)d_in[20];
  const float* wu = (const float*)d_in[21];
  const float* la_u = (const float*)d_in[22];
  const float* lb_u = (const float*)d_in[23];
  const float* wd = (const float*)d_in[24];
  const float* la_d = (const float*)d_in[25];
  const float* lb_d = (const float*)d_in[26];
  float* out = (float*)d_out;

  char* ws = (char*)d_ws;
  ushort* xn1 = (ushort*)ws;  ws += (size_t)SEQ * DIM * 2;
  ushort* qb  = (ushort*)ws;  ws += (size_t)SEQ * DIM * 2;
  ushort* kb  = (ushort*)ws;  ws += (size_t)SEQ * NKVH * HD * 2;
  ushort* vtb = (ushort*)ws;  ws += (size_t)SEQ * NKVH * HD * 2;
  ushort* ob  = (ushort*)ws;  ws += (size_t)SEQ * DIM * 2;
  float*  xmed= (float*)ws;   ws += (size_t)SEQ * DIM * 4;
  ushort* xn2 = (ushort*)ws;  ws += (size_t)SEQ * DIM * 2;
  ushort* gate= (ushort*)ws;  ws += (size_t)SEQ * FF * 2;
  ushort* up  = (ushort*)ws;  ws += (size_t)SEQ * FF * 2;
  ushort* hb  = (ushort*)ws;  ws += (size_t)SEQ * FF * 2;
  ushort* t_q = (ushort*)ws; ws += SEQ * LR * 2;
  ushort* t_k = (ushort*)ws; ws += SEQ * LR * 2;
  ushort* t_v = (ushort*)ws; ws += SEQ * LR * 2;
  ushort* t_o = (ushort*)ws; ws += SEQ * LR * 2;
  ushort* t_g = (ushort*)ws; ws += SEQ * LR * 2;
  ushort* t_u = (ushort*)ws; ws += SEQ * LR * 2;
  ushort* t_d = (ushort*)ws; ws += SEQ * LR * 2;

  // bf16 split-K partial buffers aliased onto dead regions:
  ushort* pbuf1 = (ushort*)gate;  // QKV (50 MB) / wo (32 MB): gate..hb dead then
  ushort* pbuf2 = (ushort*)xn2;   // wd (32 MB): xn2+gate+up dead then

  size_t snd = (size_t)SEQ * DIM;

  // 1) norm + fused lora-A (q,k,v share xn1)
  rmsnorm_kernel<<<SEQ, 256, 0, stream>>>(x, w1, xn1);
  lora_a_kernel<3><<<SEQ, 256, 0, stream>>>(xn1, la_q, la_k, la_v, t_q, t_k, t_v, DIM);

  // 2) fused QKV GEMM (split-K4, 384 blocks, fused dequant) -> 4-slice reduce + RoPE + V-T
  gemm256_kernel<3><<<dim3((DIM + 2048) / 256, SEQ / 256, 4), 512, 0, stream>>>(
      xn1, wq, wk, wv, lb_q, lb_k, lb_v, t_q, t_k, t_v,
      nullptr, nullptr, nullptr, DIM, DIM + 1024,
      pbuf1, SEQ, DIM + 2048, DIM, 16);
  reduce4_qkv_rope<<<SEQ * 896 / 256, 256, 0, stream>>>(pbuf1, cosT, sinT, qb, kb, vtb);

  // 3) attention
  attn_kernel<<<dim3(SEQ / 64, NH), 256, 0, stream>>>(qb, kb, vtb, ob);

  // 4) WO (split-K4, fused dequant) + residual + fused RMSNorm -> xmed, xn2
  lora_a_kernel<1><<<SEQ, 256, 0, stream>>>(ob, la_o, la_o, la_o, t_o, t_o, t_o, DIM);
  gemm256_kernel<3><<<dim3(DIM / 256, SEQ / 256, 4), 512, 0, stream>>>(
      ob, wo, wo, wo, lb_o, lb_o, lb_o, t_o, t_o, t_o,
      nullptr, nullptr, nullptr, DIM, DIM,
      pbuf1, SEQ, DIM, DIM, 16);
  reduce4_res_rms<<<SEQ, 256, 0, stream>>>(pbuf1, x, w2, xmed, xn2, snd);

  // 5) FFN: combined gate+up GEMM (N=2*FF, 448 blocks), then silu-mul
  lora_a_kernel<2><<<SEQ, 256, 0, stream>>>(xn2, la_g, la_u, la_u, t_g, t_u, t_u, DIM);
  gemm256_kernel<0><<<dim3(2 * FF / 256, SEQ / 256, 1), 512, 0, stream>>>(
      xn2, wg, wu, wu, lb_g, lb_u, lb_u, t_g, t_u, t_u,
      gate, up, up, FF, 2 * FF,
      nullptr, SEQ, 2 * FF, DIM, DIM / 64);
  silu_mul_kernel<<<SEQ * FF / 8 / 256, 256, 0, stream>>>(gate, up, hb);
  lora_a_kernel<1><<<SEQ, 256, 0, stream>>>(hb, la_d, la_d, la_d, t_d, t_d, t_d, FF);
  gemm256_kernel<3><<<dim3(DIM / 256, SEQ / 256, 4), 512, 0, stream>>>(
      hb, wd, wd, wd, lb_d, lb_d, lb_d, t_d, t_d, t_d,
      nullptr, nullptr, nullptr, DIM, DIM,
      pbuf2, SEQ, DIM, FF, FF / 4 / 64);
  reduce4_res_kernel<<<snd / 1024, 256, 0, stream>>>(pbuf2, xmed, out, snd);
}

// Round 20
// 863.478 us; speedup vs baseline: 5.7164x; 1.0000x over previous
//
#include <hip/hip_runtime.h>
#include <hip/hip_bf16.h>
#include <math.h>

#define SEQ 1024
#define DIM 4096
#define NH 32
#define HD 128
#define NKVH 8
#define FF 14336
#define LR 16

typedef __attribute__((ext_vector_type(8))) short bf16x8;
typedef __attribute__((ext_vector_type(4))) float f32x4;
typedef __attribute__((ext_vector_type(4))) ushort ushort4v;
typedef __attribute__((ext_vector_type(4))) unsigned int u32x4;

__device__ __forceinline__ ushort f2bf(float f) {
  union { float f; unsigned u; } v; v.f = f;
  unsigned r = (v.u + 0x7FFFu + ((v.u >> 16) & 1u)) >> 16;
  return (ushort)r;
}
__device__ __forceinline__ float bf2f(ushort h) {
  union { unsigned u; float f; } v; v.u = ((unsigned)h) << 16;
  return v.f;
}
__device__ __forceinline__ unsigned cvtpk(float a, float b) {
  unsigned r;
  asm("v_cvt_pk_bf16_f32 %0, %1, %2" : "=v"(r) : "v"(a), "v"(b));
  return r;
}
// sum of 4 bf16 partial slices, vectorized 4-wide
__device__ __forceinline__ float4 sum4v(const ushort* __restrict__ p, size_t idx, size_t ss) {
  float4 r = {0.f, 0.f, 0.f, 0.f};
#pragma unroll
  for (int s = 0; s < 4; s++) {
    ushort4v v = *(const ushort4v*)&p[idx + (size_t)s * ss];
    r.x += bf2f(v.x); r.y += bf2f(v.y); r.z += bf2f(v.z); r.w += bf2f(v.w);
  }
  return r;
}

__device__ __forceinline__ void gload_lds16(const void* g, void* l) {
  __builtin_amdgcn_global_load_lds(
      (const __attribute__((address_space(1))) void*)g,
      (__attribute__((address_space(3))) void*)l, 16, 0, 0);
}

// ---------------- RMSNorm: f32 in -> bf16 out ----------------
__global__ __launch_bounds__(256) void rmsnorm_kernel(const float* __restrict__ x,
                                                      const float* __restrict__ w,
                                                      ushort* __restrict__ out) {
  int row = blockIdx.x;
  int tid = threadIdx.x;
  const float* xr = x + (size_t)row * DIM;
  float vals[16];
  float s = 0.f;
#pragma unroll
  for (int c = 0; c < 4; c++) {
    float4 v = *(const float4*)&xr[(tid + c * 256) * 4];
    vals[c * 4 + 0] = v.x; vals[c * 4 + 1] = v.y;
    vals[c * 4 + 2] = v.z; vals[c * 4 + 3] = v.w;
    s += v.x * v.x + v.y * v.y + v.z * v.z + v.w * v.w;
  }
#pragma unroll
  for (int off = 32; off >= 1; off >>= 1) s += __shfl_down(s, off);
  __shared__ float wsum[4];
  __shared__ float scale_s;
  int lane = tid & 63, wv = tid >> 6;
  if (lane == 0) wsum[wv] = s;
  __syncthreads();
  if (tid == 0) {
    float t = wsum[0] + wsum[1] + wsum[2] + wsum[3];
    scale_s = rsqrtf(t / (float)DIM + 1e-5f);
  }
  __syncthreads();
  float scale = scale_s;
  ushort* orow = out + (size_t)row * DIM;
#pragma unroll
  for (int c = 0; c < 4; c++) {
    int base = (tid + c * 256) * 4;
    float4 wv4 = *(const float4*)&w[base];
    ushort4v ov;
    ov.x = f2bf(vals[c * 4 + 0] * scale * wv4.x);
    ov.y = f2bf(vals[c * 4 + 1] * scale * wv4.y);
    ov.z = f2bf(vals[c * 4 + 2] * scale * wv4.z);
    ov.w = f2bf(vals[c * 4 + 3] * scale * wv4.w);
    *(ushort4v*)&orow[base] = ov;
  }
}

// ---------------- LoRA A: t_l[m][16] = A[m] @ la_l, one row per block ----------------
template <int NL>
__global__ __launch_bounds__(256) void lora_a_kernel(
    const ushort* __restrict__ A,
    const float* __restrict__ la0, const float* __restrict__ la1,
    const float* __restrict__ la2,
    ushort* __restrict__ t0, ushort* __restrict__ t1, ushort* __restrict__ t2,
    int K) {
  int m = blockIdx.x, i = threadIdx.x;
  float acc[NL][16];
#pragma unroll
  for (int l = 0; l < NL; l++)
#pragma unroll
    for (int n = 0; n < 16; n++) acc[l][n] = 0.f;

  const ushort* Arow = A + (size_t)m * K;
  int nc = K >> 8;
  for (int c = 0; c < nc; c++) {
    int k = c * 256 + i;
    float a = bf2f(Arow[k]);
#pragma unroll
    for (int l = 0; l < NL; l++) {
      const float* lap = (l == 0 ? la0 : (l == 1 ? la1 : la2)) + (size_t)k * 16;
#pragma unroll
      for (int q = 0; q < 4; q++) {
        float4 lv = *(const float4*)&lap[q * 4];
        acc[l][q * 4 + 0] += a * lv.x;
        acc[l][q * 4 + 1] += a * lv.y;
        acc[l][q * 4 + 2] += a * lv.z;
        acc[l][q * 4 + 3] += a * lv.w;
      }
    }
  }

  __shared__ float red[256][17];
  __shared__ float red2[16][17];
#pragma unroll
  for (int l = 0; l < NL; l++) {
    __syncthreads();
#pragma unroll
    for (int n = 0; n < 16; n++) red[i][n] = acc[l][n];
    __syncthreads();
    {
      int g = i >> 4, n = i & 15;
      float s = 0.f;
#pragma unroll
      for (int j = 0; j < 16; j++) s += red[g * 16 + j][n];
      red2[g][n] = s;
    }
    __syncthreads();
    if (i < 16) {
      float s2 = 0.f;
#pragma unroll
      for (int g2 = 0; g2 < 16; g2++) s2 += red2[g2][i];
      ushort* tp = (l == 0 ? t0 : (l == 1 ? t1 : t2));
      tp[(size_t)m * LR + i] = f2bf(s2);
    }
  }
}

// ---------------- FUSED: h = silu(gate)*up -> hb; t_d[m][16] = h @ la_d ----------------
// One row per block. Reads gate+up once, writes hb, accumulates t_d from the
// QUANTIZED bf16 h (bitwise-identical to the former silu_mul + lora_a<1> pair).
__global__ __launch_bounds__(256) void silu_lora_kernel(
    const ushort* __restrict__ g, const ushort* __restrict__ u,
    const float* __restrict__ la,
    ushort* __restrict__ hb, ushort* __restrict__ t, int K) {
  int m = blockIdx.x, i = threadIdx.x;
  float acc[16];
#pragma unroll
  for (int n = 0; n < 16; n++) acc[n] = 0.f;

  const ushort* gr = g + (size_t)m * K;
  const ushort* ur = u + (size_t)m * K;
  ushort* hr = hb + (size_t)m * K;
  int nc = K >> 8;
  for (int c = 0; c < nc; c++) {
    int k = c * 256 + i;
    float gf = bf2f(gr[k]);
    float uf = bf2f(ur[k]);
    float hv = gf / (1.f + __expf(-gf)) * uf;
    ushort hq = f2bf(hv);
    hr[k] = hq;
    float a = bf2f(hq);  // quantized value, matches wd GEMM's input
    const float* lap = la + (size_t)k * 16;
#pragma unroll
    for (int q = 0; q < 4; q++) {
      float4 lv = *(const float4*)&lap[q * 4];
      acc[q * 4 + 0] += a * lv.x;
      acc[q * 4 + 1] += a * lv.y;
      acc[q * 4 + 2] += a * lv.z;
      acc[q * 4 + 3] += a * lv.w;
    }
  }

  __shared__ float red[256][17];
  __shared__ float red2[16][17];
  __syncthreads();
#pragma unroll
  for (int n = 0; n < 16; n++) red[i][n] = acc[n];
  __syncthreads();
  {
    int gg = i >> 4, n = i & 15;
    float s = 0.f;
#pragma unroll
    for (int j = 0; j < 16; j++) s += red[gg * 16 + j][n];
    red2[gg][n] = s;
  }
  __syncthreads();
  if (i < 16) {
    float s2 = 0.f;
#pragma unroll
    for (int g2 = 0; g2 < 16; g2++) s2 += red2[g2][i];
    t[(size_t)m * LR + i] = f2bf(s2);
  }
}

// ================= 256x256 GEMM, 8 waves, 8-phase dbuf, fused dequant (r15 proven core) =========
// 3-segment weight/lora/output select. WM0: bf16 out (row stride wseg); WM3: BF16 split-K
// partial slice [z][M][N]. cvt_pk dequant; panel co-location; XOR swizzle.
template <int WM>
__global__ __launch_bounds__(512) void gemm256_kernel(
    const ushort* __restrict__ A,
    const float* __restrict__ W0, const float* __restrict__ W1, const float* __restrict__ W2,
    const float* __restrict__ lb0, const float* __restrict__ lb1, const float* __restrict__ lb2,
    const ushort* __restrict__ t0, const ushort* __restrict__ t1, const ushort* __restrict__ t2,
    void* __restrict__ o0, void* __restrict__ o1, void* __restrict__ o2,
    int c1, int c2, void* __restrict__ outp, int M, int N, int K, int nkp) {
  __shared__ __align__(16) ushort As[2][256 * 64];
  __shared__ __align__(16) ushort Bs[2][256 * 64];
  int tid = threadIdx.x;
  int lane = tid & 63, wave = tid >> 6;
  int wm = wave >> 2, wn = wave & 3;

  // ---- T1 XCD swizzle + panel-sharer-adjacent decode ----
  int gx = gridDim.x, gy = gridDim.y, gz = gridDim.z;
  int flat = blockIdx.x + gx * (blockIdx.y + gy * blockIdx.z);
  int nwg = gx * gy * gz;
  int q = nwg >> 3, r = nwg & 7;
  int xcd = flat & 7;
  int wgid = (xcd < r ? xcd * (q + 1) : r * (q + 1) + (xcd - r) * q) + (flat >> 3);
  int sh = gy * gz;
  int bx = wgid / sh;
  int rem = wgid - bx * sh;
  int z = rem / gy;
  int by = rem - z * gy;

  int n0 = bx * 256, m0 = by * 256;
  int k0 = z * nkp;

  // segment select (weight + lora + out)
  const float* Wp; const float* lbp; const ushort* tp; void* osel; int nseg, wseg;
  if (n0 < c1)      { Wp = W0; lbp = lb0; tp = t0; osel = o0; nseg = n0;      wseg = c1; }
  else if (n0 < c2) { Wp = W1; lbp = lb1; tp = t1; osel = o1; nseg = n0 - c1; wseg = c2 - c1; }
  else              { Wp = W2; lbp = lb2; tp = t2; osel = o2; nseg = n0 - c2; wseg = N - c2; }

  // A staging
  int srow = tid >> 3;
  int sswz = ((tid & 7) ^ (srow & 7)) * 8;
  const ushort* Ab = A + (size_t)(m0 + srow) * K + sswz;
  // B reg-staging source (linear; swizzle at ds_write)
  const float* Wbase = Wp + (size_t)(nseg + srow) * K + (tid & 7) * 8;

  f32x4 acc[8][4] = {};
  float4 breg[8];

#define SHALF(kt, b, h)                                                       \
  _Pragma("unroll") for (int i = 2 * (h); i < 2 * (h) + 2; i++) {             \
    gload_lds16(Ab + (size_t)(i * 64) * K + (size_t)(kt) * 64,                \
                &As[b][wave * 512 + i * 4096]);                               \
  }
#define BLOAD(kt, h)                                                          \
  {                                                                           \
    const float* gp = Wbase + (size_t)((h) * 128) * K + (size_t)(kt) * 64;    \
    breg[(h) * 4 + 0] = *(const float4*)gp;                                   \
    breg[(h) * 4 + 1] = *(const float4*)(gp + 4);                             \
    breg[(h) * 4 + 2] = *(const float4*)(gp + (size_t)64 * K);                \
    breg[(h) * 4 + 3] = *(const float4*)(gp + (size_t)64 * K + 4);            \
  }
#define WRITE_B(b)                                                            \
  _Pragma("unroll") for (int h = 0; h < 2; h++)                               \
  _Pragma("unroll") for (int j = 0; j < 2; j++) {                             \
    int rr = h * 128 + j * 64 + srow;                                         \
    float4 lo = breg[h * 4 + j * 2 + 0];                                      \
    float4 hi = breg[h * 4 + j * 2 + 1];                                      \
    u32x4 v;                                                                  \
    v.x = cvtpk(lo.x, lo.y); v.y = cvtpk(lo.z, lo.w);                         \
    v.z = cvtpk(hi.x, hi.y); v.w = cvtpk(hi.z, hi.w);                         \
    *(u32x4*)&Bs[b][rr * 64 + (((tid & 7) ^ (rr & 7))) * 8] = v;              \
  }
#define LDFRAG(buf, rr, ks) \
  (*(const bf16x8*)&(buf)[(rr) * 64 + (((ks) * 4 + (lane >> 4)) ^ ((rr) & 7)) * 8])

  // ---- prologue ----
  BLOAD(k0, 0); BLOAD(k0, 1);
  SHALF(k0, 0, 0); SHALF(k0, 0, 1);
  asm volatile("s_waitcnt vmcnt(4)" ::: "memory");
  WRITE_B(0);
  if (nkp > 1) { BLOAD(k0 + 1, 0); BLOAD(k0 + 1, 1); }
  if (nkp > 1) asm volatile("s_waitcnt vmcnt(8)" ::: "memory");
  else         asm volatile("s_waitcnt vmcnt(0)" ::: "memory");
  asm volatile("s_waitcnt lgkmcnt(0)" ::: "memory");
  __builtin_amdgcn_s_barrier();
  __builtin_amdgcn_sched_barrier(0);

  for (int tau = 0; tau < nkp; tau++) {
    int b = tau & 1;
    bool s1 = (tau + 1 < nkp), s2 = (tau + 2 < nkp);
    const ushort* as = As[b];
    const ushort* bs = Bs[b];
    bf16x8 bfr[4][2];
#pragma unroll
    for (int p = 0; p < 4; p++) {
      bf16x8 af[2][2];
#pragma unroll
      for (int qq = 0; qq < 2; qq++) {
        int ra = wm * 128 + (p * 2 + qq) * 16 + (lane & 15);
#pragma unroll
        for (int ks = 0; ks < 2; ks++) af[qq][ks] = LDFRAG(as, ra, ks);
      }
      if (p == 0) {
#pragma unroll
        for (int f = 0; f < 4; f++) {
          int rb = wn * 64 + f * 16 + (lane & 15);
#pragma unroll
          for (int ks = 0; ks < 2; ks++) bfr[f][ks] = LDFRAG(bs, rb, ks);
        }
      }
      if (p == 0 && s1) { SHALF(k0 + tau + 1, b ^ 1, 0); }
      if (p == 1 && s1) { SHALF(k0 + tau + 1, b ^ 1, 1); }
      if (p == 2 && s2) { BLOAD(k0 + tau + 2, 0); }
      if (p == 3 && s2) { BLOAD(k0 + tau + 2, 1); }
      __builtin_amdgcn_sched_barrier(0);
      __builtin_amdgcn_s_barrier();
      asm volatile("s_waitcnt lgkmcnt(0)" ::: "memory");
      __builtin_amdgcn_sched_barrier(0);
      __builtin_amdgcn_s_setprio(1);
#pragma unroll
      for (int qq = 0; qq < 2; qq++)
#pragma unroll
        for (int fn = 0; fn < 4; fn++)
#pragma unroll
          for (int ks = 0; ks < 2; ks++)
            acc[p * 2 + qq][fn] = __builtin_amdgcn_mfma_f32_16x16x32_bf16(
                af[qq][ks], bfr[fn][ks], acc[p * 2 + qq][fn], 0, 0, 0);
      __builtin_amdgcn_s_setprio(0);
      __builtin_amdgcn_sched_barrier(0);
      if (p == 1 && s1) {
        asm volatile("s_waitcnt vmcnt(4)" ::: "memory");
        WRITE_B(b ^ 1);
        __builtin_amdgcn_sched_barrier(0);
      }
      if (p == 3) {
        if (s2) asm volatile("s_waitcnt vmcnt(8)" ::: "memory");
        else    asm volatile("s_waitcnt vmcnt(0)" ::: "memory");
      }
      __builtin_amdgcn_s_barrier();
      __builtin_amdgcn_sched_barrier(0);
    }
  }
#undef SHALF
#undef BLOAD
#undef WRITE_B

  // ---- LoRA K-extension (split 0 only) ----
  if (z == 0) {
#pragma unroll
    for (int it = 0; it < 2; it++) {
      int task = tid + it * 512;
      int rr = task >> 2, ls = task & 3;
      int ph = ls ^ (rr & 7);
      bf16x8 avv = {};
      bf16x8 bvv = {};
      if (ls < 2) {
        avv = *(const bf16x8*)&tp[(size_t)(m0 + rr) * LR + ls * 8];
#pragma unroll
        for (int j = 0; j < 8; j++)
          bvv[j] = (short)f2bf(lbp[(size_t)(ls * 8 + j) * wseg + nseg + rr]);
      }
      *(bf16x8*)&As[0][rr * 64 + ph * 8] = avv;
      *(bf16x8*)&Bs[0][rr * 64 + ph * 8] = bvv;
    }
    __syncthreads();
    bf16x8 af[8], bfr[4];
#pragma unroll
    for (int f = 0; f < 8; f++) {
      int ra = wm * 128 + f * 16 + (lane & 15);
      af[f] = LDFRAG(As[0], ra, 0);
    }
#pragma unroll
    for (int f = 0; f < 4; f++) {
      int rb = wn * 64 + f * 16 + (lane & 15);
      bfr[f] = LDFRAG(Bs[0], rb, 0);
    }
#pragma unroll
    for (int fm = 0; fm < 8; fm++)
#pragma unroll
      for (int fn = 0; fn < 4; fn++)
        acc[fm][fn] = __builtin_amdgcn_mfma_f32_16x16x32_bf16(af[fm], bfr[fn], acc[fm][fn], 0, 0, 0);
  }
#undef LDFRAG

  // ---- write ----
#pragma unroll
  for (int fm = 0; fm < 8; fm++) {
#pragma unroll
    for (int j = 0; j < 4; j++) {
      int mg = m0 + wm * 128 + fm * 16 + (lane >> 4) * 4 + j;
#pragma unroll
      for (int fn = 0; fn < 4; fn++) {
        int ncol = wn * 64 + fn * 16 + (lane & 15);  // col within 256-tile
        float v = acc[fm][fn][j];
        if (WM == 0) {
          ((ushort*)osel)[(size_t)mg * wseg + nseg + ncol] = f2bf(v);
        } else {
          // bf16 split-K partial slice
          ((ushort*)outp)[((size_t)z * M + mg) * (size_t)N + n0 + ncol] = f2bf(v);
        }
      }
    }
  }
}

// ---------------- QKV reduce (4 bf16 slices) + fused RoPE + V transpose ----------------
__global__ __launch_bounds__(256) void reduce4_qkv_rope(const ushort* __restrict__ p,
                                                        const float* __restrict__ ct,
                                                        const float* __restrict__ st,
                                                        ushort* __restrict__ qb,
                                                        ushort* __restrict__ kb,
                                                        ushort* __restrict__ vtb) {
  int gidx = blockIdx.x * 256 + threadIdx.x;
  int r = gidx / 896, j = gidx - r * 896;
  size_t row = (size_t)r * 6144;
  size_t ss = (size_t)SEQ * 6144;
  if (j < 640) {
    bool isq = j < 512;
    int jj = isq ? j : j - 512;
    int h = jj >> 4, d0 = (jj & 15) * 4;
    size_t base = row + (isq ? 0 : DIM) + h * 128 + d0;
    float4 x1 = sum4v(p, base, ss);
    float4 x2 = sum4v(p, base + 64, ss);
    float4 c = *(const float4*)&ct[r * HD + d0];
    float4 s = *(const float4*)&st[r * HD + d0];
    float sc = isq ? 0.08838834764831845f : 1.0f;
    ushort4v o1, o2;
    o1.x = f2bf((x1.x * c.x - x2.x * s.x) * sc);
    o1.y = f2bf((x1.y * c.y - x2.y * s.y) * sc);
    o1.z = f2bf((x1.z * c.z - x2.z * s.z) * sc);
    o1.w = f2bf((x1.w * c.w - x2.w * s.w) * sc);
    o2.x = f2bf((x2.x * c.x + x1.x * s.x) * sc);
    o2.y = f2bf((x2.y * c.y + x1.y * s.y) * sc);
    o2.z = f2bf((x2.z * c.z + x1.z * s.z) * sc);
    o2.w = f2bf((x2.w * c.w + x1.w * s.w) * sc);
    if (isq) {
      *(ushort4v*)&qb[(size_t)r * DIM + h * 128 + d0] = o1;
      *(ushort4v*)&qb[(size_t)r * DIM + h * 128 + d0 + 64] = o2;
    } else {
      *(ushort4v*)&kb[(size_t)r * 1024 + h * 128 + d0] = o1;
      *(ushort4v*)&kb[(size_t)r * 1024 + h * 128 + d0 + 64] = o2;
    }
  } else {
    int jj = j - 640;
    int c0 = jj * 4;
    size_t base = row + DIM + 1024 + c0;
    float4 sv = sum4v(p, base, ss);
    vtb[(size_t)(c0 + 0) * SEQ + r] = f2bf(sv.x);
    vtb[(size_t)(c0 + 1) * SEQ + r] = f2bf(sv.y);
    vtb[(size_t)(c0 + 2) * SEQ + r] = f2bf(sv.z);
    vtb[(size_t)(c0 + 3) * SEQ + r] = f2bf(sv.w);
  }
}

// ---------------- split-K reduce (4 bf16 slices) + residual -> f32 out ----------------
__global__ __launch_bounds__(256) void reduce4_res_kernel(const ushort* __restrict__ p,
                                                          const float* __restrict__ res,
                                                          float* __restrict__ out,
                                                          size_t sstride) {
  size_t i = ((size_t)blockIdx.x * 256 + threadIdx.x) * 4;
  float4 sv = sum4v(p, i, sstride);
  float4 r = *(const float4*)&res[i];
  float4 o;
  o.x = sv.x + r.x; o.y = sv.y + r.y; o.z = sv.z + r.z; o.w = sv.w + r.w;
  *(float4*)&out[i] = o;
}

// ---------------- split-K reduce + residual + fused RMSNorm (one row/block) ----------------
__global__ __launch_bounds__(256) void reduce4_res_rms(const ushort* __restrict__ p,
                                                       const float* __restrict__ res,
                                                       const float* __restrict__ w,
                                                       float* __restrict__ xmed,
                                                       ushort* __restrict__ xn2,
                                                       size_t sstride) {
  int row = blockIdx.x, tid = threadIdx.x;
  size_t base = (size_t)row * DIM;
  float vals[16];
  float sq = 0.f;
#pragma unroll
  for (int c = 0; c < 4; c++) {
    size_t i = base + (tid + c * 256) * 4;
    float4 sv = sum4v(p, i, sstride);
    float4 r = *(const float4*)&res[i];
    float4 v;
    v.x = sv.x + r.x; v.y = sv.y + r.y; v.z = sv.z + r.z; v.w = sv.w + r.w;
    *(float4*)&xmed[i] = v;
    vals[c * 4 + 0] = v.x; vals[c * 4 + 1] = v.y;
    vals[c * 4 + 2] = v.z; vals[c * 4 + 3] = v.w;
    sq += v.x * v.x + v.y * v.y + v.z * v.z + v.w * v.w;
  }
#pragma unroll
  for (int off = 32; off >= 1; off >>= 1) sq += __shfl_down(sq, off);
  __shared__ float wsum[4];
  __shared__ float scale_s;
  int lane = tid & 63, wv = tid >> 6;
  if (lane == 0) wsum[wv] = sq;
  __syncthreads();
  if (tid == 0) {
    float t = wsum[0] + wsum[1] + wsum[2] + wsum[3];
    scale_s = rsqrtf(t / (float)DIM + 1e-5f);
  }
  __syncthreads();
  float scale = scale_s;
#pragma unroll
  for (int c = 0; c < 4; c++) {
    int off = (tid + c * 256) * 4;
    float4 wv4 = *(const float4*)&w[off];
    ushort4v ov;
    ov.x = f2bf(vals[c * 4 + 0] * scale * wv4.x);
    ov.y = f2bf(vals[c * 4 + 1] * scale * wv4.y);
    ov.z = f2bf(vals[c * 4 + 2] * scale * wv4.z);
    ov.w = f2bf(vals[c * 4 + 3] * scale * wv4.w);
    *(ushort4v*)&xn2[base + off] = ov;
  }
}

// ---------------- Flash attention (causal, GQA 4:1), kvh-XCD co-located, LPT order ----------------
__global__ __launch_bounds__(256) void attn_kernel(const ushort* __restrict__ q,
                                                   const ushort* __restrict__ k,
                                                   const ushort* __restrict__ vt,
                                                   ushort* __restrict__ o) {
  int flat = blockIdx.x + 16 * blockIdx.y;  // 0..511
  int kvh = flat & 7;
  int idx = flat >> 3;
  int h = kvh * 4 + (idx & 3);
  int qb = 15 - (idx >> 2);                 // descending work order
  int tid = threadIdx.x, lane = tid & 63, wave = tid >> 6;
  __shared__ ushort Ks[64][136];
  __shared__ ushort Vs[128][72];
  __shared__ ushort Ps[4][16][72];

  bf16x8 qf[4];
  int qrow = qb * 64 + wave * 16 + (lane & 15);
#pragma unroll
  for (int kk = 0; kk < 4; kk++)
    qf[kk] = *(const bf16x8*)&q[(size_t)qrow * DIM + h * HD + kk * 32 + (lane >> 4) * 8];

  f32x4 oacc[8] = {};
  float mrow[4], lrow[4];
  int qr[4];
#pragma unroll
  for (int j = 0; j < 4; j++) {
    mrow[j] = -INFINITY; lrow[j] = 0.f;
    qr[j] = qb * 64 + wave * 16 + (lane >> 4) * 4 + j;
  }

  for (int kt = 0; kt <= qb; kt++) {
    int key0 = kt * 64;
#pragma unroll
    for (int c = 0; c < 4; c++) {
      int e = tid * 32 + c * 8;
      int r = e >> 7, cc = e & 127;
      *(bf16x8*)&Ks[r][cc] =
          *(const bf16x8*)&k[(size_t)(key0 + r) * (NKVH * HD) + kvh * HD + cc];
      int r2 = e >> 6, cc2 = e & 63;
      *(bf16x8*)&Vs[r2][cc2] =
          *(const bf16x8*)&vt[(size_t)(kvh * HD + r2) * SEQ + key0 + cc2];
    }
    __syncthreads();

    f32x4 sf[4] = {};
#pragma unroll
    for (int fn = 0; fn < 4; fn++)
#pragma unroll
      for (int kk = 0; kk < 4; kk++) {
        bf16x8 kf = *(const bf16x8*)&Ks[fn * 16 + (lane & 15)][kk * 32 + (lane >> 4) * 8];
        sf[fn] = __builtin_amdgcn_mfma_f32_16x16x32_bf16(qf[kk], kf, sf[fn], 0, 0, 0);
      }

#pragma unroll
    for (int fn = 0; fn < 4; fn++) {
      int key = key0 + fn * 16 + (lane & 15);
#pragma unroll
      for (int j = 0; j < 4; j++)
        if (key > qr[j]) sf[fn][j] = -INFINITY;
    }

#pragma unroll
    for (int j = 0; j < 4; j++) {
      float mx = fmaxf(fmaxf(sf[0][j], sf[1][j]), fmaxf(sf[2][j], sf[3][j]));
#pragma unroll
      for (int off = 1; off < 16; off <<= 1) mx = fmaxf(mx, __shfl_xor(mx, off));
      float mnew = fmaxf(mrow[j], mx);
      float sc = __expf(mrow[j] - mnew);
      mrow[j] = mnew;
      float rs = 0.f;
#pragma unroll
      for (int fn = 0; fn < 4; fn++) {
        float p = __expf(sf[fn][j] - mnew);
        sf[fn][j] = p;
        rs += p;
      }
#pragma unroll
      for (int off = 1; off < 16; off <<= 1) rs += __shfl_xor(rs, off);
      lrow[j] = lrow[j] * sc + rs;
#pragma unroll
      for (int f2 = 0; f2 < 8; f2++) oacc[f2][j] *= sc;
    }

#pragma unroll
    for (int fn = 0; fn < 4; fn++)
#pragma unroll
      for (int j = 0; j < 4; j++)
        Ps[wave][(lane >> 4) * 4 + j][fn * 16 + (lane & 15)] = f2bf(sf[fn][j]);

#pragma unroll
    for (int kk = 0; kk < 2; kk++) {
      bf16x8 pf = *(const bf16x8*)&Ps[wave][lane & 15][kk * 32 + (lane >> 4) * 8];
#pragma unroll
      for (int f2 = 0; f2 < 8; f2++) {
        bf16x8 vf = *(const bf16x8*)&Vs[f2 * 16 + (lane & 15)][kk * 32 + (lane >> 4) * 8];
        oacc[f2] = __builtin_amdgcn_mfma_f32_16x16x32_bf16(pf, vf, oacc[f2], 0, 0, 0);
      }
    }
    __syncthreads();
  }

#pragma unroll
  for (int j = 0; j < 4; j++) {
    float inv = 1.f / lrow[j];
#pragma unroll
    for (int f2 = 0; f2 < 8; f2++)
      o[(size_t)qr[j] * DIM + h * HD + f2 * 16 + (lane & 15)] = f2bf(oacc[f2][j] * inv);
  }
}

extern "C" void kernel_launch(void* const* d_in, const int* in_sizes, int n_in,
                              void* d_out, int out_size, void* d_ws, size_t ws_size,
                              hipStream_t stream) {
  const float* x    = (const float*)d_in[0];
  const float* w1   = (const float*)d_in[1];
  const float* w2   = (const float*)d_in[2];
  const float* cosT = (const float*)d_in[3];
  const float* sinT = (const float*)d_in[4];
  const float* wq = (const float*)d_in[6];
  const float* la_q = (const float*)d_in[7];
  const float* lb_q = (const float*)d_in[8];
  const float* wk = (const float*)d_in[9];
  const float* la_k = (const float*)d_in[10];
  const float* lb_k = (const float*)d_in[11];
  const float* wv = (const float*)d_in[12];
  const float* la_v = (const float*)d_in[13];
  const float* lb_v = (const float*)d_in[14];
  const float* wo = (const float*)d_in[15];
  const float* la_o = (const float*)d_in[16];
  const float* lb_o = (const float*)d_in[17];
  const float* wg = (const float*)d_in[18];
  const float* la_g = (const float*)d_in[19];
  const float* lb_g = (const float*)d_in[20];
  const float* wu = (const float*)d_in[21];
  const float* la_u = (const float*)d_in[22];
  const float* lb_u = (const float*)d_in[23];
  const float* wd = (const float*)d_in[24];
  const float* la_d = (const float*)d_in[25];
  const float* lb_d = (const float*)d_in[26];
  float* out = (float*)d_out;

  char* ws = (char*)d_ws;
  ushort* xn1 = (ushort*)ws;  ws += (size_t)SEQ * DIM * 2;
  ushort* qb  = (ushort*)ws;  ws += (size_t)SEQ * DIM * 2;
  ushort* kb  = (ushort*)ws;  ws += (size_t)SEQ * NKVH * HD * 2;
  ushort* vtb = (ushort*)ws;  ws += (size_t)SEQ * NKVH * HD * 2;
  ushort* ob  = (ushort*)ws;  ws += (size_t)SEQ * DIM * 2;
  float*  xmed= (float*)ws;   ws += (size_t)SEQ * DIM * 4;
  ushort* xn2 = (ushort*)ws;  ws += (size_t)SEQ * DIM * 2;
  ushort* gate= (ushort*)ws;  ws += (size_t)SEQ * FF * 2;
  ushort* up  = (ushort*)ws;  ws += (size_t)SEQ * FF * 2;
  ushort* hb  = (ushort*)ws;  ws += (size_t)SEQ * FF * 2;
  ushort* t_q = (ushort*)ws; ws += SEQ * LR * 2;
  ushort* t_k = (ushort*)ws; ws += SEQ * LR * 2;
  ushort* t_v = (ushort*)ws; ws += SEQ * LR * 2;
  ushort* t_o = (ushort*)ws; ws += SEQ * LR * 2;
  ushort* t_g = (ushort*)ws; ws += SEQ * LR * 2;
  ushort* t_u = (ushort*)ws; ws += SEQ * LR * 2;
  ushort* t_d = (ushort*)ws; ws += SEQ * LR * 2;

  // bf16 split-K partial buffers aliased onto dead regions:
  ushort* pbuf1 = (ushort*)gate;  // QKV (50 MB) / wo (32 MB): gate..hb dead then
  ushort* pbuf2 = (ushort*)xn2;   // wd (32 MB): xn2+gate+up dead then

  size_t snd = (size_t)SEQ * DIM;

  // 1) norm + fused lora-A (q,k,v share xn1)
  rmsnorm_kernel<<<SEQ, 256, 0, stream>>>(x, w1, xn1);
  lora_a_kernel<3><<<SEQ, 256, 0, stream>>>(xn1, la_q, la_k, la_v, t_q, t_k, t_v, DIM);

  // 2) fused QKV GEMM (split-K4, 384 blocks, fused dequant) -> 4-slice reduce + RoPE + V-T
  gemm256_kernel<3><<<dim3((DIM + 2048) / 256, SEQ / 256, 4), 512, 0, stream>>>(
      xn1, wq, wk, wv, lb_q, lb_k, lb_v, t_q, t_k, t_v,
      nullptr, nullptr, nullptr, DIM, DIM + 1024,
      pbuf1, SEQ, DIM + 2048, DIM, 16);
  reduce4_qkv_rope<<<SEQ * 896 / 256, 256, 0, stream>>>(pbuf1, cosT, sinT, qb, kb, vtb);

  // 3) attention
  attn_kernel<<<dim3(SEQ / 64, NH), 256, 0, stream>>>(qb, kb, vtb, ob);

  // 4) WO (split-K4, fused dequant) + residual + fused RMSNorm -> xmed, xn2
  lora_a_kernel<1><<<SEQ, 256, 0, stream>>>(ob, la_o, la_o, la_o, t_o, t_o, t_o, DIM);
  gemm256_kernel<3><<<dim3(DIM / 256, SEQ / 256, 4), 512, 0, stream>>>(
      ob, wo, wo, wo, lb_o, lb_o, lb_o, t_o, t_o, t_o,
      nullptr, nullptr, nullptr, DIM, DIM,
      pbuf1, SEQ, DIM, DIM, 16);
  reduce4_res_rms<<<SEQ, 256, 0, stream>>>(pbuf1, x, w2, xmed, xn2, snd);

  // 5) FFN: combined gate+up GEMM (N=2*FF, 448 blocks); FUSED silu+lora_d; wd GEMM
  lora_a_kernel<2><<<SEQ, 256, 0, stream>>>(xn2, la_g, la_u, la_u, t_g, t_u, t_u, DIM);
  gemm256_kernel<0><<<dim3(2 * FF / 256, SEQ / 256, 1), 512, 0, stream>>>(
      xn2, wg, wu, wu, lb_g, lb_u, lb_u, t_g, t_u, t_u,
      gate, up, up, FF, 2 * FF,
      nullptr, SEQ, 2 * FF, DIM, DIM / 64);
  silu_lora_kernel<<<SEQ, 256, 0, stream>>>(gate, up, la_d, hb, t_d, FF);
  gemm256_kernel<3><<<dim3(DIM / 256, SEQ / 256, 4), 512, 0, stream>>>(
      hb, wd, wd, wd, lb_d, lb_d, lb_d, t_d, t_d, t_d,
      nullptr, nullptr, nullptr, DIM, DIM,
      pbuf2, SEQ, DIM, FF, FF / 4 / 64);
  reduce4_res_kernel<<<snd / 1024, 256, 0, stream>>>(pbuf2, xmed, out, snd);
}